// Round 1
// baseline (1137.789 us; speedup 1.0000x reference)
//
#include <hip/hip_runtime.h>
#include <hip/hip_bf16.h>

#define LL 1024
#define DI 1536
#define N2 3072
#define ML 2048

typedef __attribute__((ext_vector_type(8))) short short8;
typedef __attribute__((ext_vector_type(4))) float f4;
typedef __attribute__((ext_vector_type(4))) float f32x4;

__device__ __forceinline__ ushort f2bf(float f) {
  union { float f; unsigned u; } v; v.f = f;
  unsigned u = v.u;
  u += 0x7fffu + ((u >> 16) & 1u);
  return (ushort)(u >> 16);
}
__device__ __forceinline__ float bf2f(ushort u) {
  union { unsigned i; float f; } w; w.i = ((unsigned)u) << 16; return w.f;
}

struct CvtSeg { const float* s; ushort* d; int n4; };
struct Cvt5 { CvtSeg seg[5]; };

// fp32 -> bf16 convert over 5 concatenated segments, vec4
__global__ void k_cvt5(Cvt5 p, int total4) {
  int i = blockIdx.x * 256 + threadIdx.x;
  if (i >= total4) return;
  int off = i, sidx = 0;
  while (sidx < 4 && off >= p.seg[sidx].n4) { off -= p.seg[sidx].n4; ++sidx; }
  f4 v = *(const f4*)(p.seg[sidx].s + (size_t)off * 4);
  ushort4 o;
  o.x = f2bf(v.x); o.y = f2bf(v.y); o.z = f2bf(v.z); o.w = f2bf(v.w);
  *(ushort4*)(p.seg[sidx].d + (size_t)off * 4) = o;
}

// dt_proj weights (1536,48) -> bf16 (2 dirs)[1536][64] zero-padded K
__global__ void k_cvtdtw(const float* __restrict__ wf, const float* __restrict__ wb,
                         ushort* __restrict__ dst) {
  int i = blockIdx.x * 256 + threadIdx.x;   // 2*1536*64
  int c = i & 63;
  int rr = i >> 6;
  int dir = rr / 1536;
  int r = rr - dir * 1536;
  const float* w = dir ? wb : wf;
  dst[i] = (c < 48) ? f2bf(w[r * 48 + c]) : (ushort)0;
}

// 128x128 tile bf16 MFMA GEMM, C[m,n] = sum_k A[m,k]*B[n,k] (both K-major)
// EPI==1: softplus(acc + bias[col]); NGUARD: N < 128 (x_proj, N=80)
template<int EPI, bool NGUARD>
__global__ __launch_bounds__(256)
void k_gemm(const ushort* __restrict__ A, const ushort* __restrict__ Bm,
            float* __restrict__ C, int M, int N, int K,
            const float* __restrict__ bias) {
  __shared__ ushort As[128][40];   // +8 pad: 80B rows, 16B aligned, ~2-way banks
  __shared__ ushort Bs[128][40];
  const int tid = threadIdx.x;
  const int m0 = blockIdx.x * 128;
  const int n0 = blockIdx.y * 128;
  const int wv = tid >> 6;
  const int lane = tid & 63;
  const int wr = (wv >> 1) * 64;
  const int wc = (wv & 1) * 64;
  const int lr = lane & 15;
  const int lk = lane >> 4;
  f32x4 acc[4][4] = {};
  for (int k0 = 0; k0 < K; k0 += 32) {
    #pragma unroll
    for (int i = 0; i < 2; ++i) {
      int e = (tid + i * 256) * 8;
      int r = e >> 5;
      int c = e & 31;
      *(short8*)(&As[r][c]) = *(const short8*)(A + (size_t)(m0 + r) * K + k0 + c);
      if (!NGUARD || (n0 + r) < N) {
        *(short8*)(&Bs[r][c]) = *(const short8*)(Bm + (size_t)(n0 + r) * K + k0 + c);
      } else {
        short8 zz = {0,0,0,0,0,0,0,0};
        *(short8*)(&Bs[r][c]) = zz;
      }
    }
    __syncthreads();
    short8 af[4], bfr[4];
    #pragma unroll
    for (int m = 0; m < 4; ++m) af[m] = *(const short8*)(&As[wr + m*16 + lr][lk*8]);
    #pragma unroll
    for (int n = 0; n < 4; ++n) bfr[n] = *(const short8*)(&Bs[wc + n*16 + lr][lk*8]);
    #pragma unroll
    for (int m = 0; m < 4; ++m)
      #pragma unroll
      for (int n = 0; n < 4; ++n)
        acc[m][n] = __builtin_amdgcn_mfma_f32_16x16x32_bf16(af[m], bfr[n], acc[m][n], 0, 0, 0);
    __syncthreads();
  }
  #pragma unroll
  for (int m = 0; m < 4; ++m) {
    int gr = m0 + wr + m * 16 + lk * 4;
    #pragma unroll
    for (int n = 0; n < 4; ++n) {
      int gc = n0 + wc + n * 16 + lr;
      if (NGUARD && gc >= N) continue;
      #pragma unroll
      for (int r = 0; r < 4; ++r) {
        float v = acc[m][n][r];
        if (EPI == 1) {
          v += bias[gc];
          v = (v > 20.f) ? v : log1pf(__expf(v));
        }
        C[(size_t)(gr + r) * N + gc] = v;
      }
    }
  }
}

// causal depthwise conv(K=4) + SiLU; dir 1 operates on time-reversed x,
// output stored in scan order (reversed time for dir 1). Writes bf16.
__global__ void k_conv(const float* __restrict__ xz,
                       const float* __restrict__ wf, const float* __restrict__ bf_,
                       const float* __restrict__ wb, const float* __restrict__ bb_,
                       ushort* __restrict__ xcbf) {
  int t = blockIdx.x * 256 + threadIdx.x;   // LL * DI/4 = 393216
  int b = blockIdx.y;
  int dir = blockIdx.z;
  int d4 = t % 384;
  int l = t / 384;
  int d = d4 * 4;
  const float* w = dir ? wb : wf;
  const float* bias = dir ? bb_ : bf_;
  float a0 = bias[d], a1 = bias[d+1], a2 = bias[d+2], a3 = bias[d+3];
  #pragma unroll
  for (int k = 0; k < 4; ++k) {
    int tt = l - 3 + k;
    if (tt >= 0) {
      int src = dir ? (LL - 1 - tt) : tt;
      f4 xv = *(const f4*)(xz + ((size_t)(b * LL + src)) * N2 + d);
      a0 += xv.x * w[(d+0)*4 + k];
      a1 += xv.y * w[(d+1)*4 + k];
      a2 += xv.z * w[(d+2)*4 + k];
      a3 += xv.w * w[(d+3)*4 + k];
    }
  }
  a0 = a0 / (1.f + __expf(-a0));
  a1 = a1 / (1.f + __expf(-a1));
  a2 = a2 / (1.f + __expf(-a2));
  a3 = a3 / (1.f + __expf(-a3));
  ushort4 o; o.x = f2bf(a0); o.y = f2bf(a1); o.z = f2bf(a2); o.w = f2bf(a3);
  *(ushort4*)(xcbf + ((size_t)dir * ML + b * LL + l) * DI + d) = o;
}

// pack dt (cols 0..47 of dtBC, stride 80) into [2][2048][64] bf16, zero-pad
__global__ void k_packdt(const float* __restrict__ dtBC, ushort* __restrict__ dtbf) {
  int i = blockIdx.x * 256 + threadIdx.x;   // 2*2048*64
  int c = i & 63;
  int bl = (i >> 6) & 2047;
  int dir = i >> 17;
  ushort v = 0;
  if (c < 48) v = f2bf(dtBC[((size_t)dir * ML + bl) * 80 + c]);
  dtbf[i] = v;
}

// selective scan: 16 lanes per (b,dir,d) channel, one n-state per lane.
// h = exp(delta*A)*h + delta*x*B;  y = sum_n h*C + x*D;  out = y*silu(z)
__global__ __launch_bounds__(256)
void k_scan(const float* __restrict__ delta_all,
            const ushort* __restrict__ xc_all,
            const float* __restrict__ dtBC_all,
            const float* __restrict__ xz,
            const float* __restrict__ Alog_f, const float* __restrict__ Df,
            const float* __restrict__ Alog_b, const float* __restrict__ Db,
            float* __restrict__ yf, float* __restrict__ yb) {
  int dir = blockIdx.z;
  int b = blockIdx.y;
  int tid = threadIdx.x;
  int lane = tid & 63;
  int wv = tid >> 6;
  int n = lane & 15;
  int grp = lane >> 4;
  int d = blockIdx.x * 16 + wv * 4 + grp;
  const float* Alog = dir ? Alog_b : Alog_f;
  const float* Dp = dir ? Db : Df;
  float Av = -__expf(Alog[d * 16 + n]);
  float Dvv = Dp[d];
  size_t base = ((size_t)dir * ML + (size_t)b * LL) * DI + d;
  const float* dptr = delta_all + base;
  const ushort* xptr = xc_all + base;
  const float* bc = dtBC_all + ((size_t)dir * ML + (size_t)b * LL) * 80;
  float* yo = dir ? yb : yf;
  float h = 0.f;
  for (int l = 0; l < LL; ++l) {
    float dl = dptr[(size_t)l * DI];
    float xv = bf2f(xptr[(size_t)l * DI]);
    float Bv = bc[l * 80 + 48 + n];
    float Cv = bc[l * 80 + 64 + n];
    float dA = __expf(dl * Av);
    h = dA * h + (dl * xv) * Bv;
    float p = h * Cv;
    p += __shfl_xor(p, 1);
    p += __shfl_xor(p, 2);
    p += __shfl_xor(p, 4);
    p += __shfl_xor(p, 8);
    if (n == 0) {
      int lo = dir ? (LL - 1 - l) : l;
      float z = xz[((size_t)b * LL + lo) * N2 + DI + d];
      float sz = z / (1.f + __expf(-z));
      yo[((size_t)b * LL + lo) * DI + d] = (p + xv * Dvv) * sz;
    }
  }
}

// y_bf = bf16(yf + yb), vec4
__global__ void k_addcvt(const float* __restrict__ a, const float* __restrict__ b,
                         ushort* __restrict__ o) {
  int i = blockIdx.x * 256 + threadIdx.x;
  f4 va = *(const f4*)(a + (size_t)i * 4);
  f4 vb = *(const f4*)(b + (size_t)i * 4);
  ushort4 u;
  u.x = f2bf(va.x + vb.x); u.y = f2bf(va.y + vb.y);
  u.z = f2bf(va.z + vb.z); u.w = f2bf(va.w + vb.w);
  *(ushort4*)(o + (size_t)i * 4) = u;
}

extern "C" void kernel_launch(void* const* d_in, const int* in_sizes, int n_in,
                              void* d_out, int out_size, void* d_ws, size_t ws_size,
                              hipStream_t stream) {
  const float* hidden      = (const float*)d_in[0];
  const float* in_proj_w   = (const float*)d_in[1];
  const float* conv_w      = (const float*)d_in[2];
  const float* conv_b      = (const float*)d_in[3];
  const float* x_proj_w    = (const float*)d_in[4];
  const float* dt_proj_w   = (const float*)d_in[5];
  const float* dt_proj_b   = (const float*)d_in[6];
  const float* A_log       = (const float*)d_in[7];
  const float* Dv          = (const float*)d_in[8];
  const float* conv_w_b    = (const float*)d_in[9];
  const float* conv_b_b    = (const float*)d_in[10];
  const float* x_proj_w_b  = (const float*)d_in[11];
  const float* dt_proj_w_b = (const float*)d_in[12];
  const float* dt_proj_b_b = (const float*)d_in[13];
  const float* A_b_log     = (const float*)d_in[14];
  const float* D_b         = (const float*)d_in[15];
  const float* out_proj_w  = (const float*)d_in[16];
  float* out = (float*)d_out;

  // fp32 workspace layout (floats)
  float* wsf   = (float*)d_ws;
  float* xz    = wsf;               // 6291456  [2048][3072]
  float* dtBC  = wsf + 6291456;     // 2x163840 [2][2048][80]
  float* delta = wsf + 6619136;     // 2x3145728 [2][2048][1536]
  float* yf    = wsf + 12910592;    // 3145728
  float* yb    = wsf + 16056320;    // 3145728
  // bf16 workspace (ushorts), starts at byte 76808192
  ushort* wsb     = (ushort*)((char*)d_ws + 76808192);
  ushort* hid_bf  = wsb;                 // 1572864
  ushort* win_bf  = wsb + 1572864;       // 2359296
  ushort* xw_bf   = wsb + 3932160;       // 2x122880
  ushort* dtw_bf  = wsb + 4177920;       // 2x98304
  ushort* wout_bf = wsb + 4374528;       // 1179648
  ushort* xc_bf   = wsb + 5554176;       // 2x3145728
  ushort* dt_bf   = wsb + 11845632;      // 2x131072
  ushort* y_bf    = wsb + 12107776;      // 3145728
  if (ws_size < 107315200) return;       // need ~107.3 MB

  Cvt5 c5;
  c5.seg[0] = { hidden,      hid_bf,            1572864 / 4 };
  c5.seg[1] = { in_proj_w,   win_bf,            2359296 / 4 };
  c5.seg[2] = { x_proj_w,    xw_bf,             122880 / 4 };
  c5.seg[3] = { x_proj_w_b,  xw_bf + 122880,    122880 / 4 };
  c5.seg[4] = { out_proj_w,  wout_bf,           1179648 / 4 };
  k_cvt5<<<5232, 256, 0, stream>>>(c5, 1339392);
  k_cvtdtw<<<768, 256, 0, stream>>>(dt_proj_w, dt_proj_w_b, dtw_bf);

  // xz = hidden @ in_proj_w.T   (2048 x 3072, K=768)
  k_gemm<0, false><<<dim3(16, 24), 256, 0, stream>>>(hid_bf, win_bf, xz, 2048, 3072, 768, nullptr);

  // conv + silu, both dirs -> xc_bf
  k_conv<<<dim3(1536, 2, 2), 256, 0, stream>>>(xz, conv_w, conv_b, conv_w_b, conv_b_b, xc_bf);

  // x_proj: (2048 x 80, K=1536), per dir
  k_gemm<0, true><<<dim3(16, 1), 256, 0, stream>>>(xc_bf, xw_bf, dtBC, 2048, 80, 1536, nullptr);
  k_gemm<0, true><<<dim3(16, 1), 256, 0, stream>>>(xc_bf + 3145728, xw_bf + 122880,
                                                   dtBC + 163840, 2048, 80, 1536, nullptr);
  k_packdt<<<1024, 256, 0, stream>>>(dtBC, dt_bf);

  // dt_proj + bias + softplus: (2048 x 1536, K=64 padded)
  k_gemm<1, false><<<dim3(16, 12), 256, 0, stream>>>(dt_bf, dtw_bf, delta, 2048, 1536, 64, dt_proj_b);
  k_gemm<1, false><<<dim3(16, 12), 256, 0, stream>>>(dt_bf + 131072, dtw_bf + 98304,
                                                     delta + 3145728, 2048, 1536, 64, dt_proj_b_b);

  // selective scan, both dirs concurrently
  k_scan<<<dim3(96, 2, 2), 256, 0, stream>>>(delta, xc_bf, dtBC, xz,
                                             A_log, Dv, A_b_log, D_b, yf, yb);

  // y_bf = bf16(yf + yb)
  k_addcvt<<<3072, 256, 0, stream>>>(yf, yb, y_bf);

  // out = y @ out_proj_w.T  (2048 x 768, K=1536)
  k_gemm<0, false><<<dim3(16, 6), 256, 0, stream>>>(y_bf, wout_bf, out, 2048, 768, 1536, nullptr);
}

// Round 2
// 516.708 us; speedup vs baseline: 2.2020x; 2.2020x over previous
//
#include <hip/hip_runtime.h>
#include <hip/hip_bf16.h>

#define LL 1024
#define DI 1536
#define N2 3072
#define ML 2048

typedef __attribute__((ext_vector_type(8))) short short8;
typedef __attribute__((ext_vector_type(4))) float f4;
typedef __attribute__((ext_vector_type(4))) float f32x4;

__device__ __forceinline__ ushort f2bf(float f) {
  union { float f; unsigned u; } v; v.f = f;
  unsigned u = v.u;
  u += 0x7fffu + ((u >> 16) & 1u);
  return (ushort)(u >> 16);
}
__device__ __forceinline__ float bf2f(ushort u) {
  union { unsigned i; float f; } w; w.i = ((unsigned)u) << 16; return w.f;
}

struct CvtSeg { const float* s; ushort* d; int n4; };
struct Cvt5 { CvtSeg seg[5]; };

// fp32 -> bf16 convert over 5 concatenated segments, vec4
__global__ void k_cvt5(Cvt5 p, int total4) {
  int i = blockIdx.x * 256 + threadIdx.x;
  if (i >= total4) return;
  int off = i, sidx = 0;
  while (sidx < 4 && off >= p.seg[sidx].n4) { off -= p.seg[sidx].n4; ++sidx; }
  f4 v = *(const f4*)(p.seg[sidx].s + (size_t)off * 4);
  ushort4 o;
  o.x = f2bf(v.x); o.y = f2bf(v.y); o.z = f2bf(v.z); o.w = f2bf(v.w);
  *(ushort4*)(p.seg[sidx].d + (size_t)off * 4) = o;
}

// dt_proj weights (1536,48) -> bf16 (2 dirs)[1536][64] zero-padded K
__global__ void k_cvtdtw(const float* __restrict__ wf, const float* __restrict__ wb,
                         ushort* __restrict__ dst) {
  int i = blockIdx.x * 256 + threadIdx.x;   // 2*1536*64
  int c = i & 63;
  int rr = i >> 6;
  int dir = rr / 1536;
  int r = rr - dir * 1536;
  const float* w = dir ? wb : wf;
  dst[i] = (c < 48) ? f2bf(w[r * 48 + c]) : (ushort)0;
}

// 128x128 tile bf16 MFMA GEMM, C[m,n] = sum_k A[m,k]*B[n,k] (both K-major)
// EPI==1: softplus(acc + bias[col]); EPI==2: also emit bf16 dt (cols<64,
// zero-padded >=48) to C2. NGUARD: N < 128 (x_proj, N=80).
// gridDim.z = #dirs; per-dir strides sA/sB/sC/sC2, bias2 = dir-1 bias.
template<int EPI, bool NGUARD>
__global__ __launch_bounds__(256)
void k_gemm(const ushort* __restrict__ A, const ushort* __restrict__ Bm,
            float* __restrict__ C, int M, int N, int K,
            const float* __restrict__ bias, const float* __restrict__ bias2,
            ushort* __restrict__ C2,
            size_t sA, size_t sB, size_t sC, size_t sC2) {
  const int dir = blockIdx.z;
  A += (size_t)dir * sA;
  Bm += (size_t)dir * sB;
  C += (size_t)dir * sC;
  if (EPI == 2) C2 += (size_t)dir * sC2;
  const float* bp = (EPI == 1) ? (dir ? bias2 : bias) : nullptr;

  __shared__ ushort As[128][40];   // +8 pad: 80B rows, 16B aligned, ~2-way banks
  __shared__ ushort Bs[128][40];
  const int tid = threadIdx.x;
  const int m0 = blockIdx.x * 128;
  const int n0 = blockIdx.y * 128;
  const int wv = tid >> 6;
  const int lane = tid & 63;
  const int wr = (wv >> 1) * 64;
  const int wc = (wv & 1) * 64;
  const int lr = lane & 15;
  const int lk = lane >> 4;
  f32x4 acc[4][4] = {};
  for (int k0 = 0; k0 < K; k0 += 32) {
    #pragma unroll
    for (int i = 0; i < 2; ++i) {
      int e = (tid + i * 256) * 8;
      int r = e >> 5;
      int c = e & 31;
      *(short8*)(&As[r][c]) = *(const short8*)(A + (size_t)(m0 + r) * K + k0 + c);
      if (!NGUARD || (n0 + r) < N) {
        *(short8*)(&Bs[r][c]) = *(const short8*)(Bm + (size_t)(n0 + r) * K + k0 + c);
      } else {
        short8 zz = {0,0,0,0,0,0,0,0};
        *(short8*)(&Bs[r][c]) = zz;
      }
    }
    __syncthreads();
    short8 af[4], bfr[4];
    #pragma unroll
    for (int m = 0; m < 4; ++m) af[m] = *(const short8*)(&As[wr + m*16 + lr][lk*8]);
    #pragma unroll
    for (int n = 0; n < 4; ++n) bfr[n] = *(const short8*)(&Bs[wc + n*16 + lr][lk*8]);
    #pragma unroll
    for (int m = 0; m < 4; ++m)
      #pragma unroll
      for (int n = 0; n < 4; ++n)
        acc[m][n] = __builtin_amdgcn_mfma_f32_16x16x32_bf16(af[m], bfr[n], acc[m][n], 0, 0, 0);
    __syncthreads();
  }
  #pragma unroll
  for (int m = 0; m < 4; ++m) {
    int gr = m0 + wr + m * 16 + lk * 4;
    #pragma unroll
    for (int n = 0; n < 4; ++n) {
      int gc = n0 + wc + n * 16 + lr;
      #pragma unroll
      for (int r = 0; r < 4; ++r) {
        float v = acc[m][n][r];
        if (EPI == 1) {
          v += bp[gc];
          v = (v > 20.f) ? v : log1pf(__expf(v));
        }
        if (!NGUARD || gc < N) C[(size_t)(gr + r) * N + gc] = v;
        if (EPI == 2) {
          if (gc < 64) C2[(size_t)(gr + r) * 64 + gc] = (gc < 48) ? f2bf(v) : (ushort)0;
        }
      }
    }
  }
}

// causal depthwise conv(K=4) + SiLU; dir 1 operates on time-reversed x,
// output stored in scan order (reversed time for dir 1). Writes bf16.
__global__ void k_conv(const float* __restrict__ xz,
                       const float* __restrict__ wf, const float* __restrict__ bf_,
                       const float* __restrict__ wb, const float* __restrict__ bb_,
                       ushort* __restrict__ xcbf) {
  int t = blockIdx.x * 256 + threadIdx.x;   // LL * DI/4 = 393216
  int b = blockIdx.y;
  int dir = blockIdx.z;
  int d4 = t % 384;
  int l = t / 384;
  int d = d4 * 4;
  const float* w = dir ? wb : wf;
  const float* bias = dir ? bb_ : bf_;
  float a0 = bias[d], a1 = bias[d+1], a2 = bias[d+2], a3 = bias[d+3];
  #pragma unroll
  for (int k = 0; k < 4; ++k) {
    int tt = l - 3 + k;
    if (tt >= 0) {
      int src = dir ? (LL - 1 - tt) : tt;
      f4 xv = *(const f4*)(xz + ((size_t)(b * LL + src)) * N2 + d);
      a0 += xv.x * w[(d+0)*4 + k];
      a1 += xv.y * w[(d+1)*4 + k];
      a2 += xv.z * w[(d+2)*4 + k];
      a3 += xv.w * w[(d+3)*4 + k];
    }
  }
  a0 = a0 / (1.f + __expf(-a0));
  a1 = a1 / (1.f + __expf(-a1));
  a2 = a2 / (1.f + __expf(-a2));
  a3 = a3 / (1.f + __expf(-a3));
  ushort4 o; o.x = f2bf(a0); o.y = f2bf(a1); o.z = f2bf(a2); o.w = f2bf(a3);
  *(ushort4*)(xcbf + ((size_t)dir * ML + b * LL + l) * DI + d) = o;
}

// ---- chunked parallel scan: 16 chunks of 64 steps ----
// K1: per (dirb, d, chunk): local scan h from 0, emit chunk-final hL and
// chunk product P of dA. 16 lanes = 16 n-states per channel.
__global__ __launch_bounds__(256)
void k_scan1(const float* __restrict__ delta_all,
             const ushort* __restrict__ xc_all,
             const float* __restrict__ dtBC_all,
             const float* __restrict__ Alog_f, const float* __restrict__ Alog_b,
             float* __restrict__ hL, float* __restrict__ P) {
  int dirb = blockIdx.z;               // 0..3
  int dir = dirb >> 1, b = dirb & 1;
  int ch = blockIdx.y;                 // 0..15
  int tid = threadIdx.x;
  int n = tid & 15;
  int g = tid >> 4;                    // 0..15
  int d = blockIdx.x * 16 + g;
  const float* Alog = dir ? Alog_b : Alog_f;
  float Av = -__expf(Alog[d * 16 + n]);
  int l0 = ch * 64;
  size_t base = ((size_t)dir * ML + (size_t)b * LL + l0) * DI + d;
  const float* dptr = delta_all + base;
  const ushort* xptr = xc_all + base;
  const float* bc = dtBC_all + ((size_t)dir * ML + (size_t)b * LL + l0) * 80;
  float h = 0.f, p = 1.f;
  #pragma unroll 4
  for (int l = 0; l < 64; ++l) {
    float dl = dptr[(size_t)l * DI];
    float xv = bf2f(xptr[(size_t)l * DI]);
    float Bv = bc[l * 80 + 48 + n];
    float dA = __expf(dl * Av);
    h = dA * h + (dl * xv) * Bv;
    p *= dA;
  }
  size_t si = (((size_t)dirb * 1536 + d) * 16 + ch) * 16 + n;
  hL[si] = h;
  P[si] = p;
}

// combine: per channel, sequential over 16 chunks -> h_in per chunk
__global__ void k_comb(const float* __restrict__ hL, const float* __restrict__ P,
                       float* __restrict__ hIn) {
  int tid = blockIdx.x * 256 + threadIdx.x;   // 6144*16 = 98304
  int n = tid & 15;
  size_t c = tid >> 4;
  float h = 0.f;
  size_t base = c * 256 + n;
  #pragma unroll
  for (int ch = 0; ch < 16; ++ch) {
    hIn[base + ch * 16] = h;
    h = P[base + ch * 16] * h + hL[base + ch * 16];
  }
}

// K2: rerun local scan seeded with h_in; fused C-contraction, D, z-gate, y.
__global__ __launch_bounds__(256)
void k_scan2(const float* __restrict__ delta_all,
             const ushort* __restrict__ xc_all,
             const float* __restrict__ dtBC_all,
             const float* __restrict__ xz,
             const float* __restrict__ Alog_f, const float* __restrict__ Df,
             const float* __restrict__ Alog_b, const float* __restrict__ Db,
             const float* __restrict__ hIn,
             float* __restrict__ yf, float* __restrict__ yb) {
  int dirb = blockIdx.z;
  int dir = dirb >> 1, b = dirb & 1;
  int ch = blockIdx.y;
  int tid = threadIdx.x;
  int n = tid & 15;
  int g = tid >> 4;
  int d = blockIdx.x * 16 + g;
  const float* Alog = dir ? Alog_b : Alog_f;
  const float* Dp = dir ? Db : Df;
  float Av = -__expf(Alog[d * 16 + n]);
  float Dvv = Dp[d];
  int l0 = ch * 64;
  size_t base = ((size_t)dir * ML + (size_t)b * LL + l0) * DI + d;
  const float* dptr = delta_all + base;
  const ushort* xptr = xc_all + base;
  const float* bc = dtBC_all + ((size_t)dir * ML + (size_t)b * LL + l0) * 80;
  float* yo = dir ? yb : yf;
  float h = hIn[(((size_t)dirb * 1536 + d) * 16 + ch) * 16 + n];
  #pragma unroll 4
  for (int l = 0; l < 64; ++l) {
    float dl = dptr[(size_t)l * DI];
    float xv = bf2f(xptr[(size_t)l * DI]);
    float Bv = bc[l * 80 + 48 + n];
    float Cv = bc[l * 80 + 64 + n];
    float dA = __expf(dl * Av);
    h = dA * h + (dl * xv) * Bv;
    float pr = h * Cv;
    pr += __shfl_xor(pr, 1);
    pr += __shfl_xor(pr, 2);
    pr += __shfl_xor(pr, 4);
    pr += __shfl_xor(pr, 8);
    if (n == 0) {
      int gl = l0 + l;
      int lo = dir ? (LL - 1 - gl) : gl;
      float z = xz[((size_t)b * LL + lo) * N2 + DI + d];
      float sz = z / (1.f + __expf(-z));
      yo[((size_t)b * LL + lo) * DI + d] = (pr + xv * Dvv) * sz;
    }
  }
}

// y_bf = bf16(yf + yb), vec4
__global__ void k_addcvt(const float* __restrict__ a, const float* __restrict__ b,
                         ushort* __restrict__ o) {
  int i = blockIdx.x * 256 + threadIdx.x;
  f4 va = *(const f4*)(a + (size_t)i * 4);
  f4 vb = *(const f4*)(b + (size_t)i * 4);
  ushort4 u;
  u.x = f2bf(va.x + vb.x); u.y = f2bf(va.y + vb.y);
  u.z = f2bf(va.z + vb.z); u.w = f2bf(va.w + vb.w);
  *(ushort4*)(o + (size_t)i * 4) = u;
}

extern "C" void kernel_launch(void* const* d_in, const int* in_sizes, int n_in,
                              void* d_out, int out_size, void* d_ws, size_t ws_size,
                              hipStream_t stream) {
  const float* hidden      = (const float*)d_in[0];
  const float* in_proj_w   = (const float*)d_in[1];
  const float* conv_w      = (const float*)d_in[2];
  const float* conv_b      = (const float*)d_in[3];
  const float* x_proj_w    = (const float*)d_in[4];
  const float* dt_proj_w   = (const float*)d_in[5];
  const float* dt_proj_b   = (const float*)d_in[6];
  const float* A_log       = (const float*)d_in[7];
  const float* Dv          = (const float*)d_in[8];
  const float* conv_w_b    = (const float*)d_in[9];
  const float* conv_b_b    = (const float*)d_in[10];
  const float* x_proj_w_b  = (const float*)d_in[11];
  const float* dt_proj_w_b = (const float*)d_in[12];
  const float* dt_proj_b_b = (const float*)d_in[13];
  const float* A_b_log     = (const float*)d_in[14];
  const float* D_b         = (const float*)d_in[15];
  const float* out_proj_w  = (const float*)d_in[16];
  float* out = (float*)d_out;

  // fp32 workspace layout (floats)
  float* wsf   = (float*)d_ws;
  float* xz    = wsf;               // 6291456  [2048][3072]
  float* dtBC  = wsf + 6291456;     // 2x163840 [2][2048][80]
  float* delta = wsf + 6619136;     // 2x3145728 [2][2048][1536]
  float* yf    = wsf + 12910592;    // 3145728
  float* yb    = wsf + 16056320;    // 3145728
  // bf16 workspace (ushorts), starts at byte 76808192
  ushort* wsb     = (ushort*)((char*)d_ws + 76808192);
  ushort* hid_bf  = wsb;                 // 1572864
  ushort* win_bf  = wsb + 1572864;       // 2359296
  ushort* xw_bf   = wsb + 3932160;       // 2x122880
  ushort* dtw_bf  = wsb + 4177920;       // 2x98304
  ushort* wout_bf = wsb + 4374528;       // 1179648
  ushort* xc_bf   = wsb + 5554176;       // 2x3145728
  ushort* dt_bf   = wsb + 11845632;      // 2x131072
  ushort* y_bf    = wsb + 12107776;      // 3145728
  if (ws_size < 107315200) return;       // need ~107.3 MB

  // scan chunk-state overlays (liveness-disjoint with their hosts):
  // hL -> yf region, P -> yb region (dead once k_comb consumed them; k_scan2
  // then writes y there). hIn -> y_bf region (consumed by k_scan2 before
  // k_addcvt writes y_bf). Each needs 1572864 floats.
  float* hL  = yf;
  float* P   = yb;
  float* hIn = (float*)y_bf;

  Cvt5 c5;
  c5.seg[0] = { hidden,      hid_bf,            1572864 / 4 };
  c5.seg[1] = { in_proj_w,   win_bf,            2359296 / 4 };
  c5.seg[2] = { x_proj_w,    xw_bf,             122880 / 4 };
  c5.seg[3] = { x_proj_w_b,  xw_bf + 122880,    122880 / 4 };
  c5.seg[4] = { out_proj_w,  wout_bf,           1179648 / 4 };
  k_cvt5<<<5232, 256, 0, stream>>>(c5, 1339392);
  k_cvtdtw<<<768, 256, 0, stream>>>(dt_proj_w, dt_proj_w_b, dtw_bf);

  // xz = hidden @ in_proj_w.T   (2048 x 3072, K=768)
  k_gemm<0, false><<<dim3(16, 24), 256, 0, stream>>>(
      hid_bf, win_bf, xz, 2048, 3072, 768, nullptr, nullptr, nullptr, 0, 0, 0, 0);

  // conv + silu, both dirs -> xc_bf
  k_conv<<<dim3(1536, 2, 2), 256, 0, stream>>>(xz, conv_w, conv_b, conv_w_b, conv_b_b, xc_bf);

  // x_proj both dirs: (2048 x 80, K=1536); fused dt pack -> dt_bf
  k_gemm<2, true><<<dim3(16, 1, 2), 256, 0, stream>>>(
      xc_bf, xw_bf, dtBC, 2048, 80, 1536, nullptr, nullptr, dt_bf,
      3145728, 122880, 163840, 131072);

  // dt_proj + bias + softplus, both dirs: (2048 x 1536, K=64 padded)
  k_gemm<1, false><<<dim3(16, 12, 2), 256, 0, stream>>>(
      dt_bf, dtw_bf, delta, 2048, 1536, 64, dt_proj_b, dt_proj_b_b, nullptr,
      131072, 98304, 3145728, 0);

  // chunked scan: K1 (local states) -> combine -> K2 (seeded, fused epilogue)
  k_scan1<<<dim3(96, 16, 4), 256, 0, stream>>>(delta, xc_bf, dtBC, A_log, A_b_log, hL, P);
  k_comb<<<384, 256, 0, stream>>>(hL, P, hIn);
  k_scan2<<<dim3(96, 16, 4), 256, 0, stream>>>(delta, xc_bf, dtBC, xz,
                                               A_log, Dv, A_b_log, D_b, hIn, yf, yb);

  // y_bf = bf16(yf + yb)
  k_addcvt<<<3072, 256, 0, stream>>>(yf, yb, y_bf);

  // out = y @ out_proj_w.T  (2048 x 768, K=1536)
  k_gemm<0, false><<<dim3(16, 6), 256, 0, stream>>>(
      y_bf, wout_bf, out, 2048, 768, 1536, nullptr, nullptr, nullptr, 0, 0, 0, 0);
}

// Round 4
// 384.929 us; speedup vs baseline: 2.9558x; 1.3423x over previous
//
#include <hip/hip_runtime.h>
#include <hip/hip_bf16.h>

#define LL 1024
#define DI 1536
#define N2 3072
#define ML 2048

typedef __attribute__((ext_vector_type(8))) short short8;
typedef __attribute__((ext_vector_type(4))) float f4;
typedef __attribute__((ext_vector_type(4))) float f32x4;

__device__ __forceinline__ ushort f2bf(float f) {
  union { float f; unsigned u; } v; v.f = f;
  unsigned u = v.u;
  u += 0x7fffu + ((u >> 16) & 1u);
  return (ushort)(u >> 16);
}
__device__ __forceinline__ float bf2f(ushort u) {
  union { unsigned i; float f; } w; w.i = ((unsigned)u) << 16; return w.f;
}

struct CvtSeg { const float* s; ushort* d; int n4; };
struct Cvt5 { CvtSeg seg[5]; };

// fp32 -> bf16 convert over 5 concatenated segments, vec4
__global__ void k_cvt5(Cvt5 p, int total4) {
  int i = blockIdx.x * 256 + threadIdx.x;
  if (i >= total4) return;
  int off = i, sidx = 0;
  while (sidx < 4 && off >= p.seg[sidx].n4) { off -= p.seg[sidx].n4; ++sidx; }
  f4 v = *(const f4*)(p.seg[sidx].s + (size_t)off * 4);
  ushort4 o;
  o.x = f2bf(v.x); o.y = f2bf(v.y); o.z = f2bf(v.z); o.w = f2bf(v.w);
  *(ushort4*)(p.seg[sidx].d + (size_t)off * 4) = o;
}

// dt_proj weights (1536,48) -> bf16 (2 dirs)[1536][64] zero-padded K
__global__ void k_cvtdtw(const float* __restrict__ wf, const float* __restrict__ wb,
                         ushort* __restrict__ dst) {
  int i = blockIdx.x * 256 + threadIdx.x;   // 2*1536*64
  int c = i & 63;
  int rr = i >> 6;
  int dir = rr / 1536;
  int r = rr - dir * 1536;
  const float* w = dir ? wb : wf;
  dst[i] = (c < 48) ? f2bf(w[r * 48 + c]) : (ushort)0;
}

// 128x128 tile bf16 MFMA GEMM, C[m,n] = sum_k A[m,k]*B[n,k] (both K-major)
// EPI==1: softplus(acc + bias[col]); EPI==2: also emit bf16 dt (cols<64,
// zero-padded >=48) to C2. NGUARD: N < 128 (x_proj, N=80).
// gridDim.z = #dirs; per-dir strides sA/sB/sC/sC2, bias2 = dir-1 bias.
template<int EPI, bool NGUARD>
__global__ __launch_bounds__(256)
void k_gemm(const ushort* __restrict__ A, const ushort* __restrict__ Bm,
            float* __restrict__ C, int M, int N, int K,
            const float* __restrict__ bias, const float* __restrict__ bias2,
            ushort* __restrict__ C2,
            size_t sA, size_t sB, size_t sC, size_t sC2) {
  const int dir = blockIdx.z;
  A += (size_t)dir * sA;
  Bm += (size_t)dir * sB;
  C += (size_t)dir * sC;
  if (EPI == 2) C2 += (size_t)dir * sC2;
  const float* bp = (EPI == 1) ? (dir ? bias2 : bias) : nullptr;

  __shared__ ushort As[128][40];   // +8 pad: 80B rows, 16B aligned, ~2-way banks
  __shared__ ushort Bs[128][40];
  const int tid = threadIdx.x;
  const int m0 = blockIdx.x * 128;
  const int n0 = blockIdx.y * 128;
  const int wv = tid >> 6;
  const int lane = tid & 63;
  const int wr = (wv >> 1) * 64;
  const int wc = (wv & 1) * 64;
  const int lr = lane & 15;
  const int lk = lane >> 4;
  f32x4 acc[4][4] = {};
  for (int k0 = 0; k0 < K; k0 += 32) {
    #pragma unroll
    for (int i = 0; i < 2; ++i) {
      int e = (tid + i * 256) * 8;
      int r = e >> 5;
      int c = e & 31;
      *(short8*)(&As[r][c]) = *(const short8*)(A + (size_t)(m0 + r) * K + k0 + c);
      if (!NGUARD || (n0 + r) < N) {
        *(short8*)(&Bs[r][c]) = *(const short8*)(Bm + (size_t)(n0 + r) * K + k0 + c);
      } else {
        short8 zz = {0,0,0,0,0,0,0,0};
        *(short8*)(&Bs[r][c]) = zz;
      }
    }
    __syncthreads();
    short8 af[4], bfr[4];
    #pragma unroll
    for (int m = 0; m < 4; ++m) af[m] = *(const short8*)(&As[wr + m*16 + lr][lk*8]);
    #pragma unroll
    for (int n = 0; n < 4; ++n) bfr[n] = *(const short8*)(&Bs[wc + n*16 + lr][lk*8]);
    #pragma unroll
    for (int m = 0; m < 4; ++m)
      #pragma unroll
      for (int n = 0; n < 4; ++n)
        acc[m][n] = __builtin_amdgcn_mfma_f32_16x16x32_bf16(af[m], bfr[n], acc[m][n], 0, 0, 0);
    __syncthreads();
  }
  #pragma unroll
  for (int m = 0; m < 4; ++m) {
    int gr = m0 + wr + m * 16 + lk * 4;
    #pragma unroll
    for (int n = 0; n < 4; ++n) {
      int gc = n0 + wc + n * 16 + lr;
      #pragma unroll
      for (int r = 0; r < 4; ++r) {
        float v = acc[m][n][r];
        if (EPI == 1) {
          v += bp[gc];
          v = (v > 20.f) ? v : log1pf(__expf(v));
        }
        if (!NGUARD || gc < N) C[(size_t)(gr + r) * N + gc] = v;
        if (EPI == 2) {
          if (gc < 64) C2[(size_t)(gr + r) * 64 + gc] = (gc < 48) ? f2bf(v) : (ushort)0;
        }
      }
    }
  }
}

// causal depthwise conv(K=4) + SiLU; dir 1 operates on time-reversed x,
// output stored in scan order (reversed time for dir 1). Writes bf16.
__global__ void k_conv(const float* __restrict__ xz,
                       const float* __restrict__ wf, const float* __restrict__ bf_,
                       const float* __restrict__ wb, const float* __restrict__ bb_,
                       ushort* __restrict__ xcbf) {
  int t = blockIdx.x * 256 + threadIdx.x;   // LL * DI/4 = 393216
  int b = blockIdx.y;
  int dir = blockIdx.z;
  int d4 = t % 384;
  int l = t / 384;
  int d = d4 * 4;
  const float* w = dir ? wb : wf;
  const float* bias = dir ? bb_ : bf_;
  float a0 = bias[d], a1 = bias[d+1], a2 = bias[d+2], a3 = bias[d+3];
  #pragma unroll
  for (int k = 0; k < 4; ++k) {
    int tt = l - 3 + k;
    if (tt >= 0) {
      int src = dir ? (LL - 1 - tt) : tt;
      f4 xv = *(const f4*)(xz + ((size_t)(b * LL + src)) * N2 + d);
      a0 += xv.x * w[(d+0)*4 + k];
      a1 += xv.y * w[(d+1)*4 + k];
      a2 += xv.z * w[(d+2)*4 + k];
      a3 += xv.w * w[(d+3)*4 + k];
    }
  }
  a0 = a0 / (1.f + __expf(-a0));
  a1 = a1 / (1.f + __expf(-a1));
  a2 = a2 / (1.f + __expf(-a2));
  a3 = a3 / (1.f + __expf(-a3));
  ushort4 o; o.x = f2bf(a0); o.y = f2bf(a1); o.z = f2bf(a2); o.w = f2bf(a3);
  *(ushort4*)(xcbf + ((size_t)dir * ML + b * LL + l) * DI + d) = o;
}

// ---- chunked parallel scan: 16 chunks of 64 steps ----
// Layout: 4 lanes per (dirb,d) channel, 4 n-states per lane (n = ns*4+j).
// Wave = 16 consecutive d (lanes 0..15) x 4 state-groups (lane>>4).
// K1: local scan from h=0 -> chunk-final hL + dA-product P. No cross-lane.
__global__ __launch_bounds__(256)
void k_scan1(const float* __restrict__ delta_all,
             const ushort* __restrict__ xc_all,
             const float* __restrict__ dtBC_all,
             const float* __restrict__ Alog_f, const float* __restrict__ Alog_b,
             float* __restrict__ hL, float* __restrict__ P) {
  int dirb = blockIdx.z;               // 0..3
  int dir = dirb >> 1, b = dirb & 1;
  int ch = blockIdx.y;                 // 0..15
  int tid = threadIdx.x;
  int lane = tid & 63;
  int wv = tid >> 6;
  int ns = lane >> 4;                  // state group 0..3
  int dl_ = lane & 15;
  int d = blockIdx.x * 64 + wv * 16 + dl_;
  const float* Alog = dir ? Alog_b : Alog_f;
  float Av[4];
  #pragma unroll
  for (int j = 0; j < 4; ++j) Av[j] = -__expf(Alog[d * 16 + ns * 4 + j]);
  int l0 = ch * 64;
  size_t base = ((size_t)dir * ML + (size_t)b * LL + l0) * DI + d;
  const float* dptr = delta_all + base;
  const ushort* xptr = xc_all + base;
  const float* bc = dtBC_all + ((size_t)dir * ML + (size_t)b * LL + l0) * 80 + 48 + ns * 4;
  float h[4] = {0.f, 0.f, 0.f, 0.f};
  float p[4] = {1.f, 1.f, 1.f, 1.f};
  #pragma unroll 4
  for (int l = 0; l < 64; ++l) {
    float dl = dptr[(size_t)l * DI];
    float xv = bf2f(xptr[(size_t)l * DI]);
    f4 Bv = *(const f4*)(bc + l * 80);
    float dbx = dl * xv;
    #pragma unroll
    for (int j = 0; j < 4; ++j) {
      float dA = __expf(dl * Av[j]);
      h[j] = dA * h[j] + dbx * Bv[j];
      p[j] *= dA;
    }
  }
  size_t si = (((size_t)dirb * 1536 + d) * 16 + ch) * 16 + ns * 4;
  f4 hv = {h[0], h[1], h[2], h[3]};
  f4 pv = {p[0], p[1], p[2], p[3]};
  *(f4*)(hL + si) = hv;
  *(f4*)(P + si) = pv;
}

// combine: per (channel,n), sequential over 16 chunks -> h_in per chunk
__global__ void k_comb(const float* __restrict__ hL, const float* __restrict__ P,
                       float* __restrict__ hIn) {
  int tid = blockIdx.x * 256 + threadIdx.x;   // 6144*16 = 98304
  int n = tid & 15;
  size_t c = tid >> 4;
  float h = 0.f;
  size_t base = c * 256 + n;
  #pragma unroll
  for (int ch = 0; ch < 16; ++ch) {
    hIn[base + ch * 16] = h;
    h = P[base + ch * 16] * h + hL[base + ch * 16];
  }
}

// K2: rerun local scan seeded with h_in; fused C-contraction + D.
// Writes RAW y (z-gating moved to k_gate). 2 shuffles per step.
__global__ __launch_bounds__(256)
void k_scan2(const float* __restrict__ delta_all,
             const ushort* __restrict__ xc_all,
             const float* __restrict__ dtBC_all,
             const float* __restrict__ Alog_f, const float* __restrict__ Df,
             const float* __restrict__ Alog_b, const float* __restrict__ Db,
             const float* __restrict__ hIn,
             float* __restrict__ yf, float* __restrict__ yb) {
  int dirb = blockIdx.z;
  int dir = dirb >> 1, b = dirb & 1;
  int ch = blockIdx.y;
  int tid = threadIdx.x;
  int lane = tid & 63;
  int wv = tid >> 6;
  int ns = lane >> 4;
  int dl_ = lane & 15;
  int d = blockIdx.x * 64 + wv * 16 + dl_;
  const float* Alog = dir ? Alog_b : Alog_f;
  const float* Dp = dir ? Db : Df;
  float Av[4];
  #pragma unroll
  for (int j = 0; j < 4; ++j) Av[j] = -__expf(Alog[d * 16 + ns * 4 + j]);
  float Dvv = Dp[d];
  int l0 = ch * 64;
  size_t base = ((size_t)dir * ML + (size_t)b * LL + l0) * DI + d;
  const float* dptr = delta_all + base;
  const ushort* xptr = xc_all + base;
  const float* bc = dtBC_all + ((size_t)dir * ML + (size_t)b * LL + l0) * 80 + 48 + ns * 4;
  float* yo = dir ? yb : yf;
  size_t hi = (((size_t)dirb * 1536 + d) * 16 + ch) * 16 + ns * 4;
  f4 h0 = *(const f4*)(hIn + hi);
  float h[4] = {h0.x, h0.y, h0.z, h0.w};
  #pragma unroll 4
  for (int l = 0; l < 64; ++l) {
    float dl = dptr[(size_t)l * DI];
    float xv = bf2f(xptr[(size_t)l * DI]);
    f4 Bv = *(const f4*)(bc + l * 80);
    f4 Cv = *(const f4*)(bc + 16 + l * 80);
    float dbx = dl * xv;
    float pr = 0.f;
    #pragma unroll
    for (int j = 0; j < 4; ++j) {
      float dA = __expf(dl * Av[j]);
      h[j] = dA * h[j] + dbx * Bv[j];
      pr += h[j] * Cv[j];
    }
    pr += __shfl_xor(pr, 16);
    pr += __shfl_xor(pr, 32);
    if (ns == 0) {
      int gl = l0 + l;
      int lo = dir ? (LL - 1 - gl) : gl;
      yo[((size_t)b * LL + lo) * DI + d] = pr + xv * Dvv;
    }
  }
}

// y_bf = bf16((yf + yb) * silu(z)), vec4 over [2048][1536]
__global__ void k_gate(const float* __restrict__ a, const float* __restrict__ b,
                       const float* __restrict__ xz, ushort* __restrict__ o) {
  int i = blockIdx.x * 256 + threadIdx.x;   // 786432 f4 groups
  int row = i / 384;
  int c4 = i - row * 384;
  f4 va = *(const f4*)(a + (size_t)i * 4);
  f4 vb = *(const f4*)(b + (size_t)i * 4);
  f4 vz = *(const f4*)(xz + (size_t)row * N2 + DI + c4 * 4);
  ushort4 u;
  float s0 = vz.x / (1.f + __expf(-vz.x));
  float s1 = vz.y / (1.f + __expf(-vz.y));
  float s2 = vz.z / (1.f + __expf(-vz.z));
  float s3 = vz.w / (1.f + __expf(-vz.w));
  u.x = f2bf((va.x + vb.x) * s0);
  u.y = f2bf((va.y + vb.y) * s1);
  u.z = f2bf((va.z + vb.z) * s2);
  u.w = f2bf((va.w + vb.w) * s3);
  *(ushort4*)(o + (size_t)i * 4) = u;
}

extern "C" void kernel_launch(void* const* d_in, const int* in_sizes, int n_in,
                              void* d_out, int out_size, void* d_ws, size_t ws_size,
                              hipStream_t stream) {
  const float* hidden      = (const float*)d_in[0];
  const float* in_proj_w   = (const float*)d_in[1];
  const float* conv_w      = (const float*)d_in[2];
  const float* conv_b      = (const float*)d_in[3];
  const float* x_proj_w    = (const float*)d_in[4];
  const float* dt_proj_w   = (const float*)d_in[5];
  const float* dt_proj_b   = (const float*)d_in[6];
  const float* A_log       = (const float*)d_in[7];
  const float* Dv          = (const float*)d_in[8];
  const float* conv_w_b    = (const float*)d_in[9];
  const float* conv_b_b    = (const float*)d_in[10];
  const float* x_proj_w_b  = (const float*)d_in[11];
  const float* dt_proj_w_b = (const float*)d_in[12];
  const float* dt_proj_b_b = (const float*)d_in[13];
  const float* A_b_log     = (const float*)d_in[14];
  const float* D_b         = (const float*)d_in[15];
  const float* out_proj_w  = (const float*)d_in[16];
  float* out = (float*)d_out;

  // fp32 workspace layout (floats)
  float* wsf   = (float*)d_ws;
  float* xz    = wsf;               // 6291456  [2048][3072]
  float* dtBC  = wsf + 6291456;     // 2x163840 [2][2048][80]
  float* delta = wsf + 6619136;     // 2x3145728 [2][2048][1536]
  float* yf    = wsf + 12910592;    // 3145728
  float* yb    = wsf + 16056320;    // 3145728
  // bf16 workspace (ushorts), starts at byte 76808192
  ushort* wsb     = (ushort*)((char*)d_ws + 76808192);
  ushort* hid_bf  = wsb;                 // 1572864
  ushort* win_bf  = wsb + 1572864;       // 2359296
  ushort* xw_bf   = wsb + 3932160;       // 2x122880
  ushort* dtw_bf  = wsb + 4177920;       // 2x98304
  ushort* wout_bf = wsb + 4374528;       // 1179648
  ushort* xc_bf   = wsb + 5554176;       // 2x3145728
  ushort* dt_bf   = wsb + 11845632;      // 2x131072
  ushort* y_bf    = wsb + 12107776;      // 3145728
  if (ws_size < 107315200) return;       // need ~107.3 MB

  // scan chunk-state overlays (liveness-disjoint with their hosts):
  // hL -> yf region, P -> yb region (dead once k_comb consumed them; k_scan2
  // then writes y there). hIn -> y_bf region (consumed by k_scan2 before
  // k_gate writes y_bf). Each needs 1572864 floats.
  float* hL  = yf;
  float* P   = yb;
  float* hIn = (float*)y_bf;

  Cvt5 c5;
  c5.seg[0] = { hidden,      hid_bf,            1572864 / 4 };
  c5.seg[1] = { in_proj_w,   win_bf,            2359296 / 4 };
  c5.seg[2] = { x_proj_w,    xw_bf,             122880 / 4 };
  c5.seg[3] = { x_proj_w_b,  xw_bf + 122880,    122880 / 4 };
  c5.seg[4] = { out_proj_w,  wout_bf,           1179648 / 4 };
  k_cvt5<<<5232, 256, 0, stream>>>(c5, 1339392);
  k_cvtdtw<<<768, 256, 0, stream>>>(dt_proj_w, dt_proj_w_b, dtw_bf);

  // xz = hidden @ in_proj_w.T   (2048 x 3072, K=768)
  k_gemm<0, false><<<dim3(16, 24), 256, 0, stream>>>(
      hid_bf, win_bf, xz, 2048, 3072, 768, nullptr, nullptr, nullptr, 0, 0, 0, 0);

  // conv + silu, both dirs -> xc_bf
  k_conv<<<dim3(1536, 2, 2), 256, 0, stream>>>(xz, conv_w, conv_b, conv_w_b, conv_b_b, xc_bf);

  // x_proj both dirs: (2048 x 80, K=1536); fused dt pack -> dt_bf
  k_gemm<2, true><<<dim3(16, 1, 2), 256, 0, stream>>>(
      xc_bf, xw_bf, dtBC, 2048, 80, 1536, nullptr, nullptr, dt_bf,
      3145728, 122880, 163840, 131072);

  // dt_proj + bias + softplus, both dirs: (2048 x 1536, K=64 padded)
  k_gemm<1, false><<<dim3(16, 12, 2), 256, 0, stream>>>(
      dt_bf, dtw_bf, delta, 2048, 1536, 64, dt_proj_b, dt_proj_b_b, nullptr,
      131072, 98304, 3145728, 0);

  // chunked scan: K1 (local states) -> combine -> K2 (seeded, fused epilogue)
  k_scan1<<<dim3(24, 16, 4), 256, 0, stream>>>(delta, xc_bf, dtBC, A_log, A_b_log, hL, P);
  k_comb<<<384, 256, 0, stream>>>(hL, P, hIn);
  k_scan2<<<dim3(24, 16, 4), 256, 0, stream>>>(delta, xc_bf, dtBC,
                                               A_log, Dv, A_b_log, D_b, hIn, yf, yb);

  // y_bf = bf16((yf + yb) * silu(z))
  k_gate<<<3072, 256, 0, stream>>>(yf, yb, xz, y_bf);

  // out = y @ out_proj_w.T  (2048 x 768, K=1536)
  k_gemm<0, false><<<dim3(16, 6), 256, 0, stream>>>(
      y_bf, wout_bf, out, 2048, 768, 1536, nullptr, nullptr, nullptr, 0, 0, 0, 0);
}

// Round 5
// 351.234 us; speedup vs baseline: 3.2394x; 1.0959x over previous
//
#include <hip/hip_runtime.h>
#include <hip/hip_bf16.h>

#define LL 1024
#define DI 1536
#define N2 3072
#define ML 2048

typedef __attribute__((ext_vector_type(8))) short short8;
typedef __attribute__((ext_vector_type(4))) float f4;
typedef __attribute__((ext_vector_type(4))) float f32x4;

__device__ __forceinline__ ushort f2bf(float f) {
  union { float f; unsigned u; } v; v.f = f;
  unsigned u = v.u;
  u += 0x7fffu + ((u >> 16) & 1u);
  return (ushort)(u >> 16);
}
__device__ __forceinline__ float bf2f(ushort u) {
  union { unsigned i; float f; } w; w.i = ((unsigned)u) << 16; return w.f;
}

struct CvtSeg { const float* s; ushort* d; int n4; };
struct Cvt5 { CvtSeg seg[5]; };

#define CVT_BLOCKS 5232

// merged: blocks [0,5232): fp32->bf16 over 5 segments; blocks [5232,6000):
// dt_proj weights (1536,48) -> bf16 [2][1536][64] zero-padded K
__global__ void k_cvt(Cvt5 p, int total4,
                      const float* __restrict__ wf, const float* __restrict__ wb,
                      ushort* __restrict__ dtw) {
  int bid = blockIdx.x;
  if (bid < CVT_BLOCKS) {
    int i = bid * 256 + threadIdx.x;
    if (i >= total4) return;
    int off = i, sidx = 0;
    while (sidx < 4 && off >= p.seg[sidx].n4) { off -= p.seg[sidx].n4; ++sidx; }
    f4 v = *(const f4*)(p.seg[sidx].s + (size_t)off * 4);
    ushort4 o;
    o.x = f2bf(v.x); o.y = f2bf(v.y); o.z = f2bf(v.z); o.w = f2bf(v.w);
    *(ushort4*)(p.seg[sidx].d + (size_t)off * 4) = o;
  } else {
    int i = (bid - CVT_BLOCKS) * 256 + threadIdx.x;   // 2*1536*64
    int c = i & 63;
    int rr = i >> 6;
    int dir = rr / 1536;
    int r = rr - dir * 1536;
    const float* w = dir ? wb : wf;
    dtw[i] = (c < 48) ? f2bf(w[r * 48 + c]) : (ushort)0;
  }
}

// 128x128 tile bf16 MFMA GEMM, C[m,n] = sum_k A[m,k]*B[n,k] (both K-major)
// EPI==0: plain. EPI==1: softplus(acc + bias[col]).
// EPI==3: split-K partial — n0=0, ks=blockIdx.y, K-range [ks*kLen, (ks+1)*kLen),
//         C += ks*sKs (sC2 slot reused as ks stride).
// NGUARD: N < 128 (x_proj, N=80). gridDim.z = #dirs; strides sA/sB/sC.
template<int EPI, bool NGUARD>
__global__ __launch_bounds__(256)
void k_gemm(const ushort* __restrict__ A, const ushort* __restrict__ Bm,
            float* __restrict__ C, int M, int N, int K,
            const float* __restrict__ bias, const float* __restrict__ bias2,
            size_t sA, size_t sB, size_t sC, size_t sKs, int kLen) {
  const int dir = blockIdx.z;
  A += (size_t)dir * sA;
  Bm += (size_t)dir * sB;
  C += (size_t)dir * sC;
  const float* bp = (EPI == 1) ? (dir ? bias2 : bias) : nullptr;

  int n0, kOff, kEnd;
  if (EPI == 3) {
    n0 = 0;
    kOff = blockIdx.y * kLen;
    kEnd = kOff + kLen;
    C += (size_t)blockIdx.y * sKs;
  } else {
    n0 = blockIdx.y * 128;
    kOff = 0;
    kEnd = K;
  }

  __shared__ ushort As[128][40];   // +8 pad: 80B rows, 16B aligned, ~2-way banks
  __shared__ ushort Bs[128][40];
  const int tid = threadIdx.x;
  const int m0 = blockIdx.x * 128;
  const int wv = tid >> 6;
  const int lane = tid & 63;
  const int wr = (wv >> 1) * 64;
  const int wc = (wv & 1) * 64;
  const int lr = lane & 15;
  const int lk = lane >> 4;
  f32x4 acc[4][4] = {};
  for (int k0 = kOff; k0 < kEnd; k0 += 32) {
    #pragma unroll
    for (int i = 0; i < 2; ++i) {
      int e = (tid + i * 256) * 8;
      int r = e >> 5;
      int c = e & 31;
      *(short8*)(&As[r][c]) = *(const short8*)(A + (size_t)(m0 + r) * K + k0 + c);
      if (!NGUARD || (n0 + r) < N) {
        *(short8*)(&Bs[r][c]) = *(const short8*)(Bm + (size_t)(n0 + r) * K + k0 + c);
      } else {
        short8 zz = {0,0,0,0,0,0,0,0};
        *(short8*)(&Bs[r][c]) = zz;
      }
    }
    __syncthreads();
    short8 af[4], bfr[4];
    #pragma unroll
    for (int m = 0; m < 4; ++m) af[m] = *(const short8*)(&As[wr + m*16 + lr][lk*8]);
    #pragma unroll
    for (int n = 0; n < 4; ++n) bfr[n] = *(const short8*)(&Bs[wc + n*16 + lr][lk*8]);
    #pragma unroll
    for (int m = 0; m < 4; ++m)
      #pragma unroll
      for (int n = 0; n < 4; ++n)
        acc[m][n] = __builtin_amdgcn_mfma_f32_16x16x32_bf16(af[m], bfr[n], acc[m][n], 0, 0, 0);
    __syncthreads();
  }
  #pragma unroll
  for (int m = 0; m < 4; ++m) {
    int gr = m0 + wr + m * 16 + lk * 4;
    #pragma unroll
    for (int n = 0; n < 4; ++n) {
      int gc = n0 + wc + n * 16 + lr;
      if (NGUARD && gc >= N) continue;
      #pragma unroll
      for (int r = 0; r < 4; ++r) {
        float v = acc[m][n][r];
        if (EPI == 1) {
          v += bp[gc];
          v = (v > 20.f) ? v : log1pf(__expf(v));
        }
        C[(size_t)(gr + r) * N + gc] = v;
      }
    }
  }
}

// split-K reduce for x_proj: sum 8 partials -> dtBC fp32; pack bf16 dt
// (cols<48 of the 80; zero-pad 48..63) -> dt_bf.
__global__ void k_xred(const float* __restrict__ partial,
                       float* __restrict__ dtBC, ushort* __restrict__ dtbf) {
  int i = blockIdx.x * 256 + threadIdx.x;   // 2*2048*20 = 81920
  int dir = i / 40960;
  int rem = i - dir * 40960;
  int row = rem / 20;
  int c4 = rem - row * 20;
  f4 s = {0.f, 0.f, 0.f, 0.f};
  #pragma unroll
  for (int ks = 0; ks < 8; ++ks) {
    f4 v = *(const f4*)(partial + (((size_t)(dir * 8 + ks) * 2048 + row) * 80 + c4 * 4));
    s.x += v.x; s.y += v.y; s.z += v.z; s.w += v.w;
  }
  *(f4*)(dtBC + ((size_t)dir * 163840 + (size_t)row * 80 + c4 * 4)) = s;
  if (c4 < 16) {
    ushort4 u;
    if (c4 < 12) { u.x = f2bf(s.x); u.y = f2bf(s.y); u.z = f2bf(s.z); u.w = f2bf(s.w); }
    else { u.x = 0; u.y = 0; u.z = 0; u.w = 0; }
    *(ushort4*)(dtbf + ((size_t)dir * 131072 + (size_t)row * 64 + c4 * 4)) = u;
  }
}

// causal depthwise conv(K=4) + SiLU; dir 1 operates on time-reversed x,
// output stored in scan order (reversed time for dir 1). Writes bf16.
__global__ void k_conv(const float* __restrict__ xz,
                       const float* __restrict__ wf, const float* __restrict__ bf_,
                       const float* __restrict__ wb, const float* __restrict__ bb_,
                       ushort* __restrict__ xcbf) {
  int t = blockIdx.x * 256 + threadIdx.x;   // LL * DI/4 = 393216
  int b = blockIdx.y;
  int dir = blockIdx.z;
  int d4 = t % 384;
  int l = t / 384;
  int d = d4 * 4;
  const float* w = dir ? wb : wf;
  const float* bias = dir ? bb_ : bf_;
  float a0 = bias[d], a1 = bias[d+1], a2 = bias[d+2], a3 = bias[d+3];
  #pragma unroll
  for (int k = 0; k < 4; ++k) {
    int tt = l - 3 + k;
    if (tt >= 0) {
      int src = dir ? (LL - 1 - tt) : tt;
      f4 xv = *(const f4*)(xz + ((size_t)(b * LL + src)) * N2 + d);
      a0 += xv.x * w[(d+0)*4 + k];
      a1 += xv.y * w[(d+1)*4 + k];
      a2 += xv.z * w[(d+2)*4 + k];
      a3 += xv.w * w[(d+3)*4 + k];
    }
  }
  a0 = a0 / (1.f + __expf(-a0));
  a1 = a1 / (1.f + __expf(-a1));
  a2 = a2 / (1.f + __expf(-a2));
  a3 = a3 / (1.f + __expf(-a3));
  ushort4 o; o.x = f2bf(a0); o.y = f2bf(a1); o.z = f2bf(a2); o.w = f2bf(a3);
  *(ushort4*)(xcbf + ((size_t)dir * ML + b * LL + l) * DI + d) = o;
}

// ---- chunked parallel scan: 16 chunks of 64 steps ----
// Layout: 4 lanes per (dirb,d) channel, 4 n-states per lane (n = ns*4+j).
// Wave = 16 consecutive d (lanes 0..15) x 4 state-groups (lane>>4).
// K1: local scan from h=0 -> chunk-final hL + dA-product P. No cross-lane.
__global__ __launch_bounds__(256)
void k_scan1(const float* __restrict__ delta_all,
             const ushort* __restrict__ xc_all,
             const float* __restrict__ dtBC_all,
             const float* __restrict__ Alog_f, const float* __restrict__ Alog_b,
             float* __restrict__ hL, float* __restrict__ P) {
  int dirb = blockIdx.z;               // 0..3
  int dir = dirb >> 1, b = dirb & 1;
  int ch = blockIdx.y;                 // 0..15
  int tid = threadIdx.x;
  int lane = tid & 63;
  int wv = tid >> 6;
  int ns = lane >> 4;                  // state group 0..3
  int dl_ = lane & 15;
  int d = blockIdx.x * 64 + wv * 16 + dl_;
  const float* Alog = dir ? Alog_b : Alog_f;
  float Av[4];
  #pragma unroll
  for (int j = 0; j < 4; ++j) Av[j] = -__expf(Alog[d * 16 + ns * 4 + j]);
  int l0 = ch * 64;
  size_t base = ((size_t)dir * ML + (size_t)b * LL + l0) * DI + d;
  const float* dptr = delta_all + base;
  const ushort* xptr = xc_all + base;
  const float* bc = dtBC_all + ((size_t)dir * ML + (size_t)b * LL + l0) * 80 + 48 + ns * 4;
  float h[4] = {0.f, 0.f, 0.f, 0.f};
  float p[4] = {1.f, 1.f, 1.f, 1.f};
  #pragma unroll 4
  for (int l = 0; l < 64; ++l) {
    float dl = dptr[(size_t)l * DI];
    float xv = bf2f(xptr[(size_t)l * DI]);
    f4 Bv = *(const f4*)(bc + l * 80);
    float dbx = dl * xv;
    #pragma unroll
    for (int j = 0; j < 4; ++j) {
      float dA = __expf(dl * Av[j]);
      h[j] = dA * h[j] + dbx * Bv[j];
      p[j] *= dA;
    }
  }
  size_t si = (((size_t)dirb * 1536 + d) * 16 + ch) * 16 + ns * 4;
  f4 hv = {h[0], h[1], h[2], h[3]};
  f4 pv = {p[0], p[1], p[2], p[3]};
  *(f4*)(hL + si) = hv;
  *(f4*)(P + si) = pv;
}

// combine: per (channel,n), sequential over 16 chunks -> h_in per chunk
__global__ void k_comb(const float* __restrict__ hL, const float* __restrict__ P,
                       float* __restrict__ hIn) {
  int tid = blockIdx.x * 256 + threadIdx.x;   // 6144*16 = 98304
  int n = tid & 15;
  size_t c = tid >> 4;
  float h = 0.f;
  size_t base = c * 256 + n;
  #pragma unroll
  for (int ch = 0; ch < 16; ++ch) {
    hIn[base + ch * 16] = h;
    h = P[base + ch * 16] * h + hL[base + ch * 16];
  }
}

// K2: rerun local scan seeded with h_in; fused C-contraction + D.
// Writes RAW y (z-gating moved to k_gate). 2 shuffles per step.
__global__ __launch_bounds__(256)
void k_scan2(const float* __restrict__ delta_all,
             const ushort* __restrict__ xc_all,
             const float* __restrict__ dtBC_all,
             const float* __restrict__ Alog_f, const float* __restrict__ Df,
             const float* __restrict__ Alog_b, const float* __restrict__ Db,
             const float* __restrict__ hIn,
             float* __restrict__ yf, float* __restrict__ yb) {
  int dirb = blockIdx.z;
  int dir = dirb >> 1, b = dirb & 1;
  int ch = blockIdx.y;
  int tid = threadIdx.x;
  int lane = tid & 63;
  int wv = tid >> 6;
  int ns = lane >> 4;
  int dl_ = lane & 15;
  int d = blockIdx.x * 64 + wv * 16 + dl_;
  const float* Alog = dir ? Alog_b : Alog_f;
  const float* Dp = dir ? Db : Df;
  float Av[4];
  #pragma unroll
  for (int j = 0; j < 4; ++j) Av[j] = -__expf(Alog[d * 16 + ns * 4 + j]);
  float Dvv = Dp[d];
  int l0 = ch * 64;
  size_t base = ((size_t)dir * ML + (size_t)b * LL + l0) * DI + d;
  const float* dptr = delta_all + base;
  const ushort* xptr = xc_all + base;
  const float* bc = dtBC_all + ((size_t)dir * ML + (size_t)b * LL + l0) * 80 + 48 + ns * 4;
  float* yo = dir ? yb : yf;
  size_t hi = (((size_t)dirb * 1536 + d) * 16 + ch) * 16 + ns * 4;
  f4 h0 = *(const f4*)(hIn + hi);
  float h[4] = {h0.x, h0.y, h0.z, h0.w};
  #pragma unroll 4
  for (int l = 0; l < 64; ++l) {
    float dl = dptr[(size_t)l * DI];
    float xv = bf2f(xptr[(size_t)l * DI]);
    f4 Bv = *(const f4*)(bc + l * 80);
    f4 Cv = *(const f4*)(bc + 16 + l * 80);
    float dbx = dl * xv;
    float pr = 0.f;
    #pragma unroll
    for (int j = 0; j < 4; ++j) {
      float dA = __expf(dl * Av[j]);
      h[j] = dA * h[j] + dbx * Bv[j];
      pr += h[j] * Cv[j];
    }
    pr += __shfl_xor(pr, 16);
    pr += __shfl_xor(pr, 32);
    if (ns == 0) {
      int gl = l0 + l;
      int lo = dir ? (LL - 1 - gl) : gl;
      yo[((size_t)b * LL + lo) * DI + d] = pr + xv * Dvv;
    }
  }
}

// y_bf = bf16((yf + yb) * silu(z)), vec4 over [2048][1536]
__global__ void k_gate(const float* __restrict__ a, const float* __restrict__ b,
                       const float* __restrict__ xz, ushort* __restrict__ o) {
  int i = blockIdx.x * 256 + threadIdx.x;   // 786432 f4 groups
  int row = i / 384;
  int c4 = i - row * 384;
  f4 va = *(const f4*)(a + (size_t)i * 4);
  f4 vb = *(const f4*)(b + (size_t)i * 4);
  f4 vz = *(const f4*)(xz + (size_t)row * N2 + DI + c4 * 4);
  ushort4 u;
  float s0 = vz.x / (1.f + __expf(-vz.x));
  float s1 = vz.y / (1.f + __expf(-vz.y));
  float s2 = vz.z / (1.f + __expf(-vz.z));
  float s3 = vz.w / (1.f + __expf(-vz.w));
  u.x = f2bf((va.x + vb.x) * s0);
  u.y = f2bf((va.y + vb.y) * s1);
  u.z = f2bf((va.z + vb.z) * s2);
  u.w = f2bf((va.w + vb.w) * s3);
  *(ushort4*)(o + (size_t)i * 4) = u;
}

extern "C" void kernel_launch(void* const* d_in, const int* in_sizes, int n_in,
                              void* d_out, int out_size, void* d_ws, size_t ws_size,
                              hipStream_t stream) {
  const float* hidden      = (const float*)d_in[0];
  const float* in_proj_w   = (const float*)d_in[1];
  const float* conv_w      = (const float*)d_in[2];
  const float* conv_b      = (const float*)d_in[3];
  const float* x_proj_w    = (const float*)d_in[4];
  const float* dt_proj_w   = (const float*)d_in[5];
  const float* dt_proj_b   = (const float*)d_in[6];
  const float* A_log       = (const float*)d_in[7];
  const float* Dv          = (const float*)d_in[8];
  const float* conv_w_b    = (const float*)d_in[9];
  const float* conv_b_b    = (const float*)d_in[10];
  const float* x_proj_w_b  = (const float*)d_in[11];
  const float* dt_proj_w_b = (const float*)d_in[12];
  const float* dt_proj_b_b = (const float*)d_in[13];
  const float* A_b_log     = (const float*)d_in[14];
  const float* D_b         = (const float*)d_in[15];
  const float* out_proj_w  = (const float*)d_in[16];
  float* out = (float*)d_out;

  // fp32 workspace layout (floats)
  float* wsf   = (float*)d_ws;
  float* xz    = wsf;               // 6291456  [2048][3072]
  float* dtBC  = wsf + 6291456;     // 2x163840 [2][2048][80]
  float* delta = wsf + 6619136;     // 2x3145728 [2][2048][1536]
  float* yf    = wsf + 12910592;    // 3145728
  float* yb    = wsf + 16056320;    // 3145728
  // bf16 workspace (ushorts), starts at byte 76808192
  ushort* wsb     = (ushort*)((char*)d_ws + 76808192);
  ushort* hid_bf  = wsb;                 // 1572864
  ushort* win_bf  = wsb + 1572864;       // 2359296
  ushort* xw_bf   = wsb + 3932160;       // 2x122880
  ushort* dtw_bf  = wsb + 4177920;       // 2x98304
  ushort* wout_bf = wsb + 4374528;       // 1179648
  ushort* xc_bf   = wsb + 5554176;       // 2x3145728
  ushort* dt_bf   = wsb + 11845632;      // 2x131072
  ushort* y_bf    = wsb + 12107776;      // 3145728
  if (ws_size < 107315200) return;       // need ~107.3 MB

  // overlays (liveness-disjoint with hosts):
  // xpart (split-K partials, 2621440 floats) -> yf region: live only between
  //   x_proj and k_xred; hL (scan1) lands there afterwards.
  // hL -> yf region, P -> yb region (dead once k_comb consumed them; k_scan2
  // then writes y there). hIn -> y_bf region (consumed by k_scan2 before
  // k_gate writes y_bf).
  float* xpart = yf;
  float* hL  = yf;
  float* P   = yb;
  float* hIn = (float*)y_bf;

  Cvt5 c5;
  c5.seg[0] = { hidden,      hid_bf,            1572864 / 4 };
  c5.seg[1] = { in_proj_w,   win_bf,            2359296 / 4 };
  c5.seg[2] = { x_proj_w,    xw_bf,             122880 / 4 };
  c5.seg[3] = { x_proj_w_b,  xw_bf + 122880,    122880 / 4 };
  c5.seg[4] = { out_proj_w,  wout_bf,           1179648 / 4 };
  k_cvt<<<CVT_BLOCKS + 768, 256, 0, stream>>>(c5, 1339392, dt_proj_w, dt_proj_w_b, dtw_bf);

  // xz = hidden @ in_proj_w.T   (2048 x 3072, K=768)
  k_gemm<0, false><<<dim3(16, 24), 256, 0, stream>>>(
      hid_bf, win_bf, xz, 2048, 3072, 768, nullptr, nullptr, 0, 0, 0, 0, 0);

  // conv + silu, both dirs -> xc_bf
  k_conv<<<dim3(1536, 2, 2), 256, 0, stream>>>(xz, conv_w, conv_b, conv_w_b, conv_b_b, xc_bf);

  // x_proj both dirs, split-K 8x192: (2048 x 80, K=1536) -> partials
  k_gemm<3, true><<<dim3(16, 8, 2), 256, 0, stream>>>(
      xc_bf, xw_bf, xpart, 2048, 80, 1536, nullptr, nullptr,
      3145728, 122880, 1310720, 163840, 192);
  // reduce partials -> dtBC fp32 + dt_bf bf16 (padded)
  k_xred<<<320, 256, 0, stream>>>(xpart, dtBC, dt_bf);

  // dt_proj + bias + softplus, both dirs: (2048 x 1536, K=64 padded)
  k_gemm<1, false><<<dim3(16, 12, 2), 256, 0, stream>>>(
      dt_bf, dtw_bf, delta, 2048, 1536, 64, dt_proj_b, dt_proj_b_b,
      131072, 98304, 3145728, 0, 0);

  // chunked scan: K1 (local states) -> combine -> K2 (seeded, fused epilogue)
  k_scan1<<<dim3(24, 16, 4), 256, 0, stream>>>(delta, xc_bf, dtBC, A_log, A_b_log, hL, P);
  k_comb<<<384, 256, 0, stream>>>(hL, P, hIn);
  k_scan2<<<dim3(24, 16, 4), 256, 0, stream>>>(delta, xc_bf, dtBC,
                                               A_log, Dv, A_b_log, D_b, hIn, yf, yb);

  // y_bf = bf16((yf + yb) * silu(z))
  k_gate<<<3072, 256, 0, stream>>>(yf, yb, xz, y_bf);

  // out = y @ out_proj_w.T  (2048 x 768, K=1536)
  k_gemm<0, false><<<dim3(16, 6), 256, 0, stream>>>(
      y_bf, wout_bf, out, 2048, 768, 1536, nullptr, nullptr, 0, 0, 0, 0, 0);
}

// Round 6
// 318.821 us; speedup vs baseline: 3.5687x; 1.1017x over previous
//
#include <hip/hip_runtime.h>
#include <hip/hip_bf16.h>

#define LL 1024
#define DI 1536
#define N2 3072
#define ML 2048

typedef __attribute__((ext_vector_type(8))) short short8;
typedef __attribute__((ext_vector_type(4))) float f4;
typedef __attribute__((ext_vector_type(4))) float f32x4;

__device__ __forceinline__ ushort f2bf(float f) {
  union { float f; unsigned u; } v; v.f = f;
  unsigned u = v.u;
  u += 0x7fffu + ((u >> 16) & 1u);
  return (ushort)(u >> 16);
}
__device__ __forceinline__ float bf2f(ushort u) {
  union { unsigned i; float f; } w; w.i = ((unsigned)u) << 16; return w.f;
}

// async global->LDS, 16B per lane; lds dest = wave-uniform base + lane*16
__device__ __forceinline__ void gload16(const ushort* g, ushort* l) {
  __builtin_amdgcn_global_load_lds(
      (const __attribute__((address_space(1))) unsigned int*)g,
      (__attribute__((address_space(3))) unsigned int*)l, 16, 0, 0);
}

struct CvtSeg { const float* s; ushort* d; int n4; };
struct Cvt5 { CvtSeg seg[5]; };

#define CVT_BLOCKS 5232

// merged: blocks [0,5232): fp32->bf16 over 5 segments; blocks [5232,6000):
// dt_proj weights (1536,48) -> bf16 [2][1536][64] zero-padded K
__global__ void k_cvt(Cvt5 p, int total4,
                      const float* __restrict__ wf, const float* __restrict__ wb,
                      ushort* __restrict__ dtw) {
  int bid = blockIdx.x;
  if (bid < CVT_BLOCKS) {
    int i = bid * 256 + threadIdx.x;
    if (i >= total4) return;
    int off = i, sidx = 0;
    while (sidx < 4 && off >= p.seg[sidx].n4) { off -= p.seg[sidx].n4; ++sidx; }
    f4 v = *(const f4*)(p.seg[sidx].s + (size_t)off * 4);
    ushort4 o;
    o.x = f2bf(v.x); o.y = f2bf(v.y); o.z = f2bf(v.z); o.w = f2bf(v.w);
    *(ushort4*)(p.seg[sidx].d + (size_t)off * 4) = o;
  } else {
    int i = (bid - CVT_BLOCKS) * 256 + threadIdx.x;   // 2*1536*64
    int c = i & 63;
    int rr = i >> 6;
    int dir = rr / 1536;
    int r = rr - dir * 1536;
    const float* w = dir ? wb : wf;
    dtw[i] = (c < 48) ? f2bf(w[r * 48 + c]) : (ushort)0;
  }
}

// 128x128 tile bf16 MFMA GEMM, m97 structure: global_load_lds(16B) staging
// into LINEAR LDS [128][32], C[m,n] = sum_k A[m,k]*B[n,k] (both K-major).
// EPI==0: plain. EPI==1: softplus(acc + bias[col]).
// KS>1: split-K, blockIdx.y = nt*KS + ks, K-range [ks*kLen,(ks+1)*kLen),
//       C += ks*sKs (partials; no epilogue).
// NGUARD: N < 128 (x_proj, N=80) — B stages garbage rows >=N (memory-safe,
// columns are independent in MFMA), guarded at C-write.
template<int EPI, bool NGUARD, int KS>
__global__ __launch_bounds__(256)
void k_gemm(const ushort* __restrict__ A, const ushort* __restrict__ Bm,
            float* __restrict__ C, int M, int N, int K,
            const float* __restrict__ bias, const float* __restrict__ bias2,
            size_t sA, size_t sB, size_t sC, size_t sKs, int kLen) {
  const int dir = blockIdx.z;
  A += (size_t)dir * sA;
  Bm += (size_t)dir * sB;
  C += (size_t)dir * sC;
  const float* bp = (EPI == 1) ? (dir ? bias2 : bias) : nullptr;

  int n0, kOff, kEnd;
  if (KS > 1) {
    int yb_ = blockIdx.y;
    int nt = yb_ / KS, ks = yb_ - nt * KS;
    n0 = nt * 128;
    kOff = ks * kLen;
    kEnd = kOff + kLen;
    C += (size_t)ks * sKs;
  } else {
    n0 = blockIdx.y * 128;
    kOff = 0;
    kEnd = K;
  }

  __shared__ ushort As[128 * 32];   // linear, row-major [128][32]
  __shared__ ushort Bs[128 * 32];
  const int tid = threadIdx.x;
  const int m0 = blockIdx.x * 128;
  const int wv = tid >> 6;
  const int lane = tid & 63;
  const int wr = (wv >> 1) * 64;
  const int wc = (wv & 1) * 64;
  const int lr = lane & 15;
  const int lk = lane >> 4;
  f32x4 acc[4][4] = {};
  for (int k0 = kOff; k0 < kEnd; k0 += 32) {
    // stage: e=(tid+i*256)*8 elems; r=e>>5, c=e&31; LDS linear = e*2 bytes
    #pragma unroll
    for (int i = 0; i < 2; ++i) {
      int e = (tid + i * 256) * 8;
      int r = e >> 5;
      int c = e & 31;
      gload16(A + (size_t)(m0 + r) * K + k0 + c, &As[(i * 256 + wv * 64) * 8]);
      gload16(Bm + (size_t)(n0 + r) * K + k0 + c, &Bs[(i * 256 + wv * 64) * 8]);
    }
    __syncthreads();
    short8 af[4], bfr[4];
    #pragma unroll
    for (int m = 0; m < 4; ++m) af[m] = *(const short8*)(&As[(wr + m*16 + lr) * 32 + lk*8]);
    #pragma unroll
    for (int n = 0; n < 4; ++n) bfr[n] = *(const short8*)(&Bs[(wc + n*16 + lr) * 32 + lk*8]);
    #pragma unroll
    for (int m = 0; m < 4; ++m)
      #pragma unroll
      for (int n = 0; n < 4; ++n)
        acc[m][n] = __builtin_amdgcn_mfma_f32_16x16x32_bf16(af[m], bfr[n], acc[m][n], 0, 0, 0);
    __syncthreads();
  }
  #pragma unroll
  for (int m = 0; m < 4; ++m) {
    int gr = m0 + wr + m * 16 + lk * 4;
    #pragma unroll
    for (int n = 0; n < 4; ++n) {
      int gc = n0 + wc + n * 16 + lr;
      if (NGUARD && gc >= N) continue;
      #pragma unroll
      for (int r = 0; r < 4; ++r) {
        float v = acc[m][n][r];
        if (EPI == 1) {
          v += bp[gc];
          v = (v > 20.f) ? v : log1pf(__expf(v));
        }
        C[(size_t)(gr + r) * N + gc] = v;
      }
    }
  }
}

// split-K reduce for x_proj: sum 8 partials -> dtBC fp32; pack bf16 dt
// (cols<48 of the 80; zero-pad 48..63) -> dt_bf.
__global__ void k_xred(const float* __restrict__ partial,
                       float* __restrict__ dtBC, ushort* __restrict__ dtbf) {
  int i = blockIdx.x * 256 + threadIdx.x;   // 2*2048*20 = 81920
  int dir = i / 40960;
  int rem = i - dir * 40960;
  int row = rem / 20;
  int c4 = rem - row * 20;
  f4 s = {0.f, 0.f, 0.f, 0.f};
  #pragma unroll
  for (int ks = 0; ks < 8; ++ks) {
    f4 v = *(const f4*)(partial + (((size_t)(dir * 8 + ks) * 2048 + row) * 80 + c4 * 4));
    s.x += v.x; s.y += v.y; s.z += v.z; s.w += v.w;
  }
  *(f4*)(dtBC + ((size_t)dir * 163840 + (size_t)row * 80 + c4 * 4)) = s;
  if (c4 < 16) {
    ushort4 u;
    if (c4 < 12) { u.x = f2bf(s.x); u.y = f2bf(s.y); u.z = f2bf(s.z); u.w = f2bf(s.w); }
    else { u.x = 0; u.y = 0; u.z = 0; u.w = 0; }
    *(ushort4*)(dtbf + ((size_t)dir * 131072 + (size_t)row * 64 + c4 * 4)) = u;
  }
}

// split-K reduce for out_proj: sum 4 partials -> out
__global__ void k_ored(const float* __restrict__ part, float* __restrict__ out) {
  int i = blockIdx.x * 256 + threadIdx.x;   // 2048*768/4 = 393216
  f4 s = {0.f, 0.f, 0.f, 0.f};
  #pragma unroll
  for (int ks = 0; ks < 4; ++ks) {
    f4 v = *(const f4*)(part + (size_t)ks * 1572864 + (size_t)i * 4);
    s.x += v.x; s.y += v.y; s.z += v.z; s.w += v.w;
  }
  *(f4*)(out + (size_t)i * 4) = s;
}

// causal depthwise conv(K=4) + SiLU; dir 1 operates on time-reversed x,
// output stored in scan order (reversed time for dir 1). Writes bf16.
__global__ void k_conv(const float* __restrict__ xz,
                       const float* __restrict__ wf, const float* __restrict__ bf_,
                       const float* __restrict__ wb, const float* __restrict__ bb_,
                       ushort* __restrict__ xcbf) {
  int t = blockIdx.x * 256 + threadIdx.x;   // LL * DI/4 = 393216
  int b = blockIdx.y;
  int dir = blockIdx.z;
  int d4 = t % 384;
  int l = t / 384;
  int d = d4 * 4;
  const float* w = dir ? wb : wf;
  const float* bias = dir ? bb_ : bf_;
  float a0 = bias[d], a1 = bias[d+1], a2 = bias[d+2], a3 = bias[d+3];
  #pragma unroll
  for (int k = 0; k < 4; ++k) {
    int tt = l - 3 + k;
    if (tt >= 0) {
      int src = dir ? (LL - 1 - tt) : tt;
      f4 xv = *(const f4*)(xz + ((size_t)(b * LL + src)) * N2 + d);
      a0 += xv.x * w[(d+0)*4 + k];
      a1 += xv.y * w[(d+1)*4 + k];
      a2 += xv.z * w[(d+2)*4 + k];
      a3 += xv.w * w[(d+3)*4 + k];
    }
  }
  a0 = a0 / (1.f + __expf(-a0));
  a1 = a1 / (1.f + __expf(-a1));
  a2 = a2 / (1.f + __expf(-a2));
  a3 = a3 / (1.f + __expf(-a3));
  ushort4 o; o.x = f2bf(a0); o.y = f2bf(a1); o.z = f2bf(a2); o.w = f2bf(a3);
  *(ushort4*)(xcbf + ((size_t)dir * ML + b * LL + l) * DI + d) = o;
}

// ---- chunked parallel scan: 16 chunks of 64 steps ----
// Layout: 4 lanes per (dirb,d) channel, 4 n-states per lane (n = ns*4+j).
// K1: local scan from h=0 -> chunk-final hL + dA-product P. No cross-lane.
__global__ __launch_bounds__(256)
void k_scan1(const float* __restrict__ delta_all,
             const ushort* __restrict__ xc_all,
             const float* __restrict__ dtBC_all,
             const float* __restrict__ Alog_f, const float* __restrict__ Alog_b,
             float* __restrict__ hL, float* __restrict__ P) {
  int dirb = blockIdx.z;               // 0..3
  int dir = dirb >> 1, b = dirb & 1;
  int ch = blockIdx.y;                 // 0..15
  int tid = threadIdx.x;
  int lane = tid & 63;
  int wv = tid >> 6;
  int ns = lane >> 4;                  // state group 0..3
  int dl_ = lane & 15;
  int d = blockIdx.x * 64 + wv * 16 + dl_;
  const float* Alog = dir ? Alog_b : Alog_f;
  float Av[4];
  #pragma unroll
  for (int j = 0; j < 4; ++j) Av[j] = -__expf(Alog[d * 16 + ns * 4 + j]);
  int l0 = ch * 64;
  size_t base = ((size_t)dir * ML + (size_t)b * LL + l0) * DI + d;
  const float* dptr = delta_all + base;
  const ushort* xptr = xc_all + base;
  const float* bc = dtBC_all + ((size_t)dir * ML + (size_t)b * LL + l0) * 80 + 48 + ns * 4;
  float h[4] = {0.f, 0.f, 0.f, 0.f};
  float p[4] = {1.f, 1.f, 1.f, 1.f};
  #pragma unroll 4
  for (int l = 0; l < 64; ++l) {
    float dl = dptr[(size_t)l * DI];
    float xv = bf2f(xptr[(size_t)l * DI]);
    f4 Bv = *(const f4*)(bc + l * 80);
    float dbx = dl * xv;
    #pragma unroll
    for (int j = 0; j < 4; ++j) {
      float dA = __expf(dl * Av[j]);
      h[j] = dA * h[j] + dbx * Bv[j];
      p[j] *= dA;
    }
  }
  size_t si = (((size_t)dirb * 1536 + d) * 16 + ch) * 16 + ns * 4;
  f4 hv = {h[0], h[1], h[2], h[3]};
  f4 pv = {p[0], p[1], p[2], p[3]};
  *(f4*)(hL + si) = hv;
  *(f4*)(P + si) = pv;
}

// combine: per (channel,n), sequential over 16 chunks -> h_in per chunk
__global__ void k_comb(const float* __restrict__ hL, const float* __restrict__ P,
                       float* __restrict__ hIn) {
  int tid = blockIdx.x * 256 + threadIdx.x;   // 6144*16 = 98304
  int n = tid & 15;
  size_t c = tid >> 4;
  float h = 0.f;
  size_t base = c * 256 + n;
  #pragma unroll
  for (int ch = 0; ch < 16; ++ch) {
    hIn[base + ch * 16] = h;
    h = P[base + ch * 16] * h + hL[base + ch * 16];
  }
}

// K2: rerun local scan seeded with h_in; fused C-contraction + D.
// Writes RAW y (z-gating moved to k_gate). 2 shuffles per step.
__global__ __launch_bounds__(256)
void k_scan2(const float* __restrict__ delta_all,
             const ushort* __restrict__ xc_all,
             const float* __restrict__ dtBC_all,
             const float* __restrict__ Alog_f, const float* __restrict__ Df,
             const float* __restrict__ Alog_b, const float* __restrict__ Db,
             const float* __restrict__ hIn,
             float* __restrict__ yf, float* __restrict__ yb) {
  int dirb = blockIdx.z;
  int dir = dirb >> 1, b = dirb & 1;
  int ch = blockIdx.y;
  int tid = threadIdx.x;
  int lane = tid & 63;
  int wv = tid >> 6;
  int ns = lane >> 4;
  int dl_ = lane & 15;
  int d = blockIdx.x * 64 + wv * 16 + dl_;
  const float* Alog = dir ? Alog_b : Alog_f;
  const float* Dp = dir ? Db : Df;
  float Av[4];
  #pragma unroll
  for (int j = 0; j < 4; ++j) Av[j] = -__expf(Alog[d * 16 + ns * 4 + j]);
  float Dvv = Dp[d];
  int l0 = ch * 64;
  size_t base = ((size_t)dir * ML + (size_t)b * LL + l0) * DI + d;
  const float* dptr = delta_all + base;
  const ushort* xptr = xc_all + base;
  const float* bc = dtBC_all + ((size_t)dir * ML + (size_t)b * LL + l0) * 80 + 48 + ns * 4;
  float* yo = dir ? yb : yf;
  size_t hi = (((size_t)dirb * 1536 + d) * 16 + ch) * 16 + ns * 4;
  f4 h0 = *(const f4*)(hIn + hi);
  float h[4] = {h0.x, h0.y, h0.z, h0.w};
  #pragma unroll 4
  for (int l = 0; l < 64; ++l) {
    float dl = dptr[(size_t)l * DI];
    float xv = bf2f(xptr[(size_t)l * DI]);
    f4 Bv = *(const f4*)(bc + l * 80);
    f4 Cv = *(const f4*)(bc + 16 + l * 80);
    float dbx = dl * xv;
    float pr = 0.f;
    #pragma unroll
    for (int j = 0; j < 4; ++j) {
      float dA = __expf(dl * Av[j]);
      h[j] = dA * h[j] + dbx * Bv[j];
      pr += h[j] * Cv[j];
    }
    pr += __shfl_xor(pr, 16);
    pr += __shfl_xor(pr, 32);
    if (ns == 0) {
      int gl = l0 + l;
      int lo = dir ? (LL - 1 - gl) : gl;
      yo[((size_t)b * LL + lo) * DI + d] = pr + xv * Dvv;
    }
  }
}

// y_bf = bf16((yf + yb) * silu(z)), vec4 over [2048][1536]
__global__ void k_gate(const float* __restrict__ a, const float* __restrict__ b,
                       const float* __restrict__ xz, ushort* __restrict__ o) {
  int i = blockIdx.x * 256 + threadIdx.x;   // 786432 f4 groups
  int row = i / 384;
  int c4 = i - row * 384;
  f4 va = *(const f4*)(a + (size_t)i * 4);
  f4 vb = *(const f4*)(b + (size_t)i * 4);
  f4 vz = *(const f4*)(xz + (size_t)row * N2 + DI + c4 * 4);
  ushort4 u;
  float s0 = vz.x / (1.f + __expf(-vz.x));
  float s1 = vz.y / (1.f + __expf(-vz.y));
  float s2 = vz.z / (1.f + __expf(-vz.z));
  float s3 = vz.w / (1.f + __expf(-vz.w));
  u.x = f2bf((va.x + vb.x) * s0);
  u.y = f2bf((va.y + vb.y) * s1);
  u.z = f2bf((va.z + vb.z) * s2);
  u.w = f2bf((va.w + vb.w) * s3);
  *(ushort4*)(o + (size_t)i * 4) = u;
}

extern "C" void kernel_launch(void* const* d_in, const int* in_sizes, int n_in,
                              void* d_out, int out_size, void* d_ws, size_t ws_size,
                              hipStream_t stream) {
  const float* hidden      = (const float*)d_in[0];
  const float* in_proj_w   = (const float*)d_in[1];
  const float* conv_w      = (const float*)d_in[2];
  const float* conv_b      = (const float*)d_in[3];
  const float* x_proj_w    = (const float*)d_in[4];
  const float* dt_proj_w   = (const float*)d_in[5];
  const float* dt_proj_b   = (const float*)d_in[6];
  const float* A_log       = (const float*)d_in[7];
  const float* Dv          = (const float*)d_in[8];
  const float* conv_w_b    = (const float*)d_in[9];
  const float* conv_b_b    = (const float*)d_in[10];
  const float* x_proj_w_b  = (const float*)d_in[11];
  const float* dt_proj_w_b = (const float*)d_in[12];
  const float* dt_proj_b_b = (const float*)d_in[13];
  const float* A_b_log     = (const float*)d_in[14];
  const float* D_b         = (const float*)d_in[15];
  const float* out_proj_w  = (const float*)d_in[16];
  float* out = (float*)d_out;

  // fp32 workspace layout (floats)
  float* wsf   = (float*)d_ws;
  float* xz    = wsf;               // 6291456  [2048][3072]
  float* dtBC  = wsf + 6291456;     // 2x163840 [2][2048][80]
  float* delta = wsf + 6619136;     // 2x3145728 [2][2048][1536]
  float* yf    = wsf + 12910592;    // 3145728
  float* yb    = wsf + 16056320;    // 3145728
  // bf16 workspace (ushorts), starts at byte 76808192
  ushort* wsb     = (ushort*)((char*)d_ws + 76808192);
  ushort* hid_bf  = wsb;                 // 1572864
  ushort* win_bf  = wsb + 1572864;       // 2359296
  ushort* xw_bf   = wsb + 3932160;       // 2x122880
  ushort* dtw_bf  = wsb + 4177920;       // 2x98304
  ushort* wout_bf = wsb + 4374528;       // 1179648
  ushort* xc_bf   = wsb + 5554176;       // 2x3145728
  ushort* dt_bf   = wsb + 11845632;      // 2x131072
  ushort* y_bf    = wsb + 12107776;      // 3145728
  if (ws_size < 107315200) return;       // need ~107.3 MB

  // overlays (liveness-disjoint with hosts):
  // xpart (x_proj split-K partials, 10.5 MB) -> yf region (dead until scan1's
  //   hL lands there after k_xred).
  // opart (out_proj split-K partials, 25.2 MB) -> delta region (dead after
  //   scan2; out_proj runs after k_gate).
  // hL -> yf, P -> yb, hIn -> y_bf (same liveness argument as before).
  float* xpart = yf;
  float* opart = delta;
  float* hL  = yf;
  float* P   = yb;
  float* hIn = (float*)y_bf;

  Cvt5 c5;
  c5.seg[0] = { hidden,      hid_bf,            1572864 / 4 };
  c5.seg[1] = { in_proj_w,   win_bf,            2359296 / 4 };
  c5.seg[2] = { x_proj_w,    xw_bf,             122880 / 4 };
  c5.seg[3] = { x_proj_w_b,  xw_bf + 122880,    122880 / 4 };
  c5.seg[4] = { out_proj_w,  wout_bf,           1179648 / 4 };
  k_cvt<<<CVT_BLOCKS + 768, 256, 0, stream>>>(c5, 1339392, dt_proj_w, dt_proj_w_b, dtw_bf);

  // xz = hidden @ in_proj_w.T   (2048 x 3072, K=768)
  k_gemm<0, false, 1><<<dim3(16, 24), 256, 0, stream>>>(
      hid_bf, win_bf, xz, 2048, 3072, 768, nullptr, nullptr, 0, 0, 0, 0, 0);

  // conv + silu, both dirs -> xc_bf
  k_conv<<<dim3(1536, 2, 2), 256, 0, stream>>>(xz, conv_w, conv_b, conv_w_b, conv_b_b, xc_bf);

  // x_proj both dirs, split-K 8x192: (2048 x 80, K=1536) -> partials
  k_gemm<0, true, 8><<<dim3(16, 8, 2), 256, 0, stream>>>(
      xc_bf, xw_bf, xpart, 2048, 80, 1536, nullptr, nullptr,
      3145728, 122880, 1310720, 163840, 192);
  // reduce partials -> dtBC fp32 + dt_bf bf16 (padded)
  k_xred<<<320, 256, 0, stream>>>(xpart, dtBC, dt_bf);

  // dt_proj + bias + softplus, both dirs: (2048 x 1536, K=64 padded)
  k_gemm<1, false, 1><<<dim3(16, 12, 2), 256, 0, stream>>>(
      dt_bf, dtw_bf, delta, 2048, 1536, 64, dt_proj_b, dt_proj_b_b,
      131072, 98304, 3145728, 0, 0);

  // chunked scan: K1 (local states) -> combine -> K2 (seeded, fused epilogue)
  k_scan1<<<dim3(24, 16, 4), 256, 0, stream>>>(delta, xc_bf, dtBC, A_log, A_b_log, hL, P);
  k_comb<<<384, 256, 0, stream>>>(hL, P, hIn);
  k_scan2<<<dim3(24, 16, 4), 256, 0, stream>>>(delta, xc_bf, dtBC,
                                               A_log, Dv, A_b_log, D_b, hIn, yf, yb);

  // y_bf = bf16((yf + yb) * silu(z))
  k_gate<<<3072, 256, 0, stream>>>(yf, yb, xz, y_bf);

  // out = y @ out_proj_w.T  (2048 x 768, K=1536), split-K 4x384 -> partials
  k_gemm<0, false, 4><<<dim3(16, 24), 256, 0, stream>>>(
      y_bf, wout_bf, opart, 2048, 768, 1536, nullptr, nullptr,
      0, 0, 0, 1572864, 384);
  // reduce partials -> out
  k_ored<<<1536, 256, 0, stream>>>(opart, out);
}

// Round 7
// 281.792 us; speedup vs baseline: 4.0377x; 1.1314x over previous
//
#include <hip/hip_runtime.h>
#include <hip/hip_bf16.h>

#define LL 1024
#define DI 1536
#define N2 3072
#define ML 2048

typedef __attribute__((ext_vector_type(8))) short short8;
typedef __attribute__((ext_vector_type(4))) float f4;
typedef __attribute__((ext_vector_type(4))) float f32x4;

__device__ __forceinline__ ushort f2bf(float f) {
  union { float f; unsigned u; } v; v.f = f;
  unsigned u = v.u;
  u += 0x7fffu + ((u >> 16) & 1u);
  return (ushort)(u >> 16);
}
__device__ __forceinline__ float bf2f(ushort u) {
  union { unsigned i; float f; } w; w.i = ((unsigned)u) << 16; return w.f;
}

// async global->LDS, 16B per lane; lds dest = wave-uniform base + lane*16
__device__ __forceinline__ void gload16(const ushort* g, ushort* l) {
  __builtin_amdgcn_global_load_lds(
      (const __attribute__((address_space(1))) unsigned int*)g,
      (__attribute__((address_space(3))) unsigned int*)l, 16, 0, 0);
}

struct CvtSeg { const float* s; ushort* d; int n4; };
struct Cvt5 { CvtSeg seg[5]; };

#define CVT_BLOCKS 5232

// merged: blocks [0,5232): fp32->bf16 over 5 segments; blocks [5232,6000):
// dt_proj weights (1536,48) -> bf16 [2][1536][64] zero-padded K
__global__ void k_cvt(Cvt5 p, int total4,
                      const float* __restrict__ wf, const float* __restrict__ wb,
                      ushort* __restrict__ dtw) {
  int bid = blockIdx.x;
  if (bid < CVT_BLOCKS) {
    int i = bid * 256 + threadIdx.x;
    if (i >= total4) return;
    int off = i, sidx = 0;
    while (sidx < 4 && off >= p.seg[sidx].n4) { off -= p.seg[sidx].n4; ++sidx; }
    f4 v = *(const f4*)(p.seg[sidx].s + (size_t)off * 4);
    ushort4 o;
    o.x = f2bf(v.x); o.y = f2bf(v.y); o.z = f2bf(v.z); o.w = f2bf(v.w);
    *(ushort4*)(p.seg[sidx].d + (size_t)off * 4) = o;
  } else {
    int i = (bid - CVT_BLOCKS) * 256 + threadIdx.x;   // 2*1536*64
    int c = i & 63;
    int rr = i >> 6;
    int dir = rr / 1536;
    int r = rr - dir * 1536;
    const float* w = dir ? wb : wf;
    dtw[i] = (c < 48) ? f2bf(w[r * 48 + c]) : (ushort)0;
  }
}

// 128x128 tile bf16 MFMA GEMM, m97 structure: global_load_lds(16B) staging
// into LINEAR LDS [128][32], C[m,n] = sum_k A[m,k]*B[n,k] (both K-major).
// EPI==0: plain. EPI==1: softplus(acc + bias[col]).
// KS>1: split-K, blockIdx.y = nt*KS + ks, K-range [ks*kLen,(ks+1)*kLen),
//       C += ks*sKs (partials; no epilogue).
// NGUARD: N < 128 (x_proj, N=80) — B stages garbage rows >=N (memory-safe,
// columns are independent in MFMA), guarded at C-write.
template<int EPI, bool NGUARD, int KS>
__global__ __launch_bounds__(256)
void k_gemm(const ushort* __restrict__ A, const ushort* __restrict__ Bm,
            float* __restrict__ C, int M, int N, int K,
            const float* __restrict__ bias, const float* __restrict__ bias2,
            size_t sA, size_t sB, size_t sC, size_t sKs, int kLen) {
  const int dir = blockIdx.z;
  A += (size_t)dir * sA;
  Bm += (size_t)dir * sB;
  C += (size_t)dir * sC;
  const float* bp = (EPI == 1) ? (dir ? bias2 : bias) : nullptr;

  int n0, kOff, kEnd;
  if (KS > 1) {
    int yb_ = blockIdx.y;
    int nt = yb_ / KS, ks = yb_ - nt * KS;
    n0 = nt * 128;
    kOff = ks * kLen;
    kEnd = kOff + kLen;
    C += (size_t)ks * sKs;
  } else {
    n0 = blockIdx.y * 128;
    kOff = 0;
    kEnd = K;
  }

  __shared__ ushort As[128 * 32];   // linear, row-major [128][32]
  __shared__ ushort Bs[128 * 32];
  const int tid = threadIdx.x;
  const int m0 = blockIdx.x * 128;
  const int wv = tid >> 6;
  const int lane = tid & 63;
  const int wr = (wv >> 1) * 64;
  const int wc = (wv & 1) * 64;
  const int lr = lane & 15;
  const int lk = lane >> 4;
  f32x4 acc[4][4] = {};
  for (int k0 = kOff; k0 < kEnd; k0 += 32) {
    // stage: e=(tid+i*256)*8 elems; r=e>>5, c=e&31; LDS linear = e*2 bytes
    #pragma unroll
    for (int i = 0; i < 2; ++i) {
      int e = (tid + i * 256) * 8;
      int r = e >> 5;
      int c = e & 31;
      gload16(A + (size_t)(m0 + r) * K + k0 + c, &As[(i * 256 + wv * 64) * 8]);
      gload16(Bm + (size_t)(n0 + r) * K + k0 + c, &Bs[(i * 256 + wv * 64) * 8]);
    }
    __syncthreads();
    short8 af[4], bfr[4];
    #pragma unroll
    for (int m = 0; m < 4; ++m) af[m] = *(const short8*)(&As[(wr + m*16 + lr) * 32 + lk*8]);
    #pragma unroll
    for (int n = 0; n < 4; ++n) bfr[n] = *(const short8*)(&Bs[(wc + n*16 + lr) * 32 + lk*8]);
    #pragma unroll
    for (int m = 0; m < 4; ++m)
      #pragma unroll
      for (int n = 0; n < 4; ++n)
        acc[m][n] = __builtin_amdgcn_mfma_f32_16x16x32_bf16(af[m], bfr[n], acc[m][n], 0, 0, 0);
    __syncthreads();
  }
  #pragma unroll
  for (int m = 0; m < 4; ++m) {
    int gr = m0 + wr + m * 16 + lk * 4;
    #pragma unroll
    for (int n = 0; n < 4; ++n) {
      int gc = n0 + wc + n * 16 + lr;
      if (NGUARD && gc >= N) continue;
      #pragma unroll
      for (int r = 0; r < 4; ++r) {
        float v = acc[m][n][r];
        if (EPI == 1) {
          v += bp[gc];
          v = (v > 20.f) ? v : log1pf(__expf(v));
        }
        C[(size_t)(gr + r) * N + gc] = v;
      }
    }
  }
}

// split-K reduce for x_proj: sum 8 partials -> dtBC fp32; pack bf16 dt
// (cols<48 of the 80; zero-pad 48..63) -> dt_bf.
__global__ void k_xred(const float* __restrict__ partial,
                       float* __restrict__ dtBC, ushort* __restrict__ dtbf) {
  int i = blockIdx.x * 256 + threadIdx.x;   // 2*2048*20 = 81920
  int dir = i / 40960;
  int rem = i - dir * 40960;
  int row = rem / 20;
  int c4 = rem - row * 20;
  f4 s = {0.f, 0.f, 0.f, 0.f};
  #pragma unroll
  for (int ks = 0; ks < 8; ++ks) {
    f4 v = *(const f4*)(partial + (((size_t)(dir * 8 + ks) * 2048 + row) * 80 + c4 * 4));
    s.x += v.x; s.y += v.y; s.z += v.z; s.w += v.w;
  }
  *(f4*)(dtBC + ((size_t)dir * 163840 + (size_t)row * 80 + c4 * 4)) = s;
  if (c4 < 16) {
    ushort4 u;
    if (c4 < 12) { u.x = f2bf(s.x); u.y = f2bf(s.y); u.z = f2bf(s.z); u.w = f2bf(s.w); }
    else { u.x = 0; u.y = 0; u.z = 0; u.w = 0; }
    *(ushort4*)(dtbf + ((size_t)dir * 131072 + (size_t)row * 64 + c4 * 4)) = u;
  }
}

// split-K reduce for out_proj: sum 4 partials -> out
__global__ void k_ored(const float* __restrict__ part, float* __restrict__ out) {
  int i = blockIdx.x * 256 + threadIdx.x;   // 2048*768/4 = 393216
  f4 s = {0.f, 0.f, 0.f, 0.f};
  #pragma unroll
  for (int ks = 0; ks < 4; ++ks) {
    f4 v = *(const f4*)(part + (size_t)ks * 1572864 + (size_t)i * 4);
    s.x += v.x; s.y += v.y; s.z += v.z; s.w += v.w;
  }
  *(f4*)(out + (size_t)i * 4) = s;
}

// causal depthwise conv(K=4) + SiLU, BOTH dirs in one x pass.
// Thread owns one f4 column (4 channels) and R=8 consecutive l; register
// sliding window x[l0-3 .. l0+10] (14 f4). dir0@l uses taps x[l-3..l] with
// w[0..3]; dir1 (scan pos LL-1-l) uses taps x[l..l+3] with w[3],w[2],w[1],w[0].
// OOB taps are zero (causal padding of fwd / reversed sequence).
#define CONV_R 8
__global__ __launch_bounds__(192)
void k_conv2(const float* __restrict__ xz,
             const float* __restrict__ wf, const float* __restrict__ bf_,
             const float* __restrict__ wb, const float* __restrict__ bb_,
             ushort* __restrict__ xcbf) {
  int d4 = blockIdx.z * 192 + threadIdx.x;   // 0..383
  int b = blockIdx.y;
  int l0 = blockIdx.x * CONV_R;
  int d = d4 * 4;
  // weights: 16 consecutive floats per dir starting at wf+d*4 ([c][k])
  f4 w0[4], w1[4];
  #pragma unroll
  for (int c = 0; c < 4; ++c) {
    w0[c] = *(const f4*)(wf + (size_t)d * 4 + c * 4);
    w1[c] = *(const f4*)(wb + (size_t)d * 4 + c * 4);
  }
  f4 bias0 = *(const f4*)(bf_ + d);
  f4 bias1 = *(const f4*)(bb_ + d);
  f4 win[CONV_R + 6];
  #pragma unroll
  for (int j = 0; j < CONV_R + 6; ++j) {
    int t = l0 - 3 + j;
    if (t >= 0 && t < LL) {
      win[j] = *(const f4*)(xz + ((size_t)(b * LL + t)) * N2 + d);
    } else {
      f4 z = {0.f, 0.f, 0.f, 0.f};
      win[j] = z;
    }
  }
  #pragma unroll
  for (int i = 0; i < CONV_R; ++i) {
    int l = l0 + i;
    float a0[4], a1[4];
    #pragma unroll
    for (int c = 0; c < 4; ++c) { a0[c] = bias0[c]; a1[c] = bias1[c]; }
    #pragma unroll
    for (int k = 0; k < 4; ++k) {
      f4 xv0 = win[i + k];        // x[l-3+k]
      f4 xv1 = win[i + 3 + k];    // x[l+k]
      #pragma unroll
      for (int c = 0; c < 4; ++c) {
        a0[c] += xv0[c] * w0[c][k];
        a1[c] += xv1[c] * w1[c][3 - k];
      }
    }
    ushort4 o0, o1;
    #pragma unroll
    for (int c = 0; c < 4; ++c) {
      a0[c] = a0[c] / (1.f + __expf(-a0[c]));
      a1[c] = a1[c] / (1.f + __expf(-a1[c]));
    }
    o0.x = f2bf(a0[0]); o0.y = f2bf(a0[1]); o0.z = f2bf(a0[2]); o0.w = f2bf(a0[3]);
    o1.x = f2bf(a1[0]); o1.y = f2bf(a1[1]); o1.z = f2bf(a1[2]); o1.w = f2bf(a1[3]);
    *(ushort4*)(xcbf + ((size_t)(b * LL + l)) * DI + d) = o0;
    *(ushort4*)(xcbf + ((size_t)(ML + b * LL + (LL - 1 - l))) * DI + d) = o1;
  }
}

// ---- chunked parallel scan: 16 chunks of 64 steps ----
// Layout: 4 lanes per (dirb,d) channel, 4 n-states per lane (n = ns*4+j).
// K1: local scan from h=0 -> chunk-final hL + dA-product P. No cross-lane.
__global__ __launch_bounds__(256)
void k_scan1(const float* __restrict__ delta_all,
             const ushort* __restrict__ xc_all,
             const float* __restrict__ dtBC_all,
             const float* __restrict__ Alog_f, const float* __restrict__ Alog_b,
             float* __restrict__ hL, float* __restrict__ P) {
  int dirb = blockIdx.z;               // 0..3
  int dir = dirb >> 1, b = dirb & 1;
  int ch = blockIdx.y;                 // 0..15
  int tid = threadIdx.x;
  int lane = tid & 63;
  int wv = tid >> 6;
  int ns = lane >> 4;                  // state group 0..3
  int dl_ = lane & 15;
  int d = blockIdx.x * 64 + wv * 16 + dl_;
  const float* Alog = dir ? Alog_b : Alog_f;
  float Av[4];
  #pragma unroll
  for (int j = 0; j < 4; ++j) Av[j] = -__expf(Alog[d * 16 + ns * 4 + j]);
  int l0 = ch * 64;
  size_t base = ((size_t)dir * ML + (size_t)b * LL + l0) * DI + d;
  const float* dptr = delta_all + base;
  const ushort* xptr = xc_all + base;
  const float* bc = dtBC_all + ((size_t)dir * ML + (size_t)b * LL + l0) * 80 + 48 + ns * 4;
  float h[4] = {0.f, 0.f, 0.f, 0.f};
  float p[4] = {1.f, 1.f, 1.f, 1.f};
  #pragma unroll 4
  for (int l = 0; l < 64; ++l) {
    float dl = dptr[(size_t)l * DI];
    float xv = bf2f(xptr[(size_t)l * DI]);
    f4 Bv = *(const f4*)(bc + l * 80);
    float dbx = dl * xv;
    #pragma unroll
    for (int j = 0; j < 4; ++j) {
      float dA = __expf(dl * Av[j]);
      h[j] = dA * h[j] + dbx * Bv[j];
      p[j] *= dA;
    }
  }
  size_t si = (((size_t)dirb * 1536 + d) * 16 + ch) * 16 + ns * 4;
  f4 hv = {h[0], h[1], h[2], h[3]};
  f4 pv = {p[0], p[1], p[2], p[3]};
  *(f4*)(hL + si) = hv;
  *(f4*)(P + si) = pv;
}

// combine: per (channel,n), sequential over 16 chunks -> h_in per chunk
__global__ void k_comb(const float* __restrict__ hL, const float* __restrict__ P,
                       float* __restrict__ hIn) {
  int tid = blockIdx.x * 256 + threadIdx.x;   // 6144*16 = 98304
  int n = tid & 15;
  size_t c = tid >> 4;
  float h = 0.f;
  size_t base = c * 256 + n;
  #pragma unroll
  for (int ch = 0; ch < 16; ++ch) {
    hIn[base + ch * 16] = h;
    h = P[base + ch * 16] * h + hL[base + ch * 16];
  }
}

// K2: rerun local scan seeded with h_in; fused C-contraction + D.
// Writes RAW y (z-gating moved to k_gate). 2 shuffles per step.
__global__ __launch_bounds__(256)
void k_scan2(const float* __restrict__ delta_all,
             const ushort* __restrict__ xc_all,
             const float* __restrict__ dtBC_all,
             const float* __restrict__ Alog_f, const float* __restrict__ Df,
             const float* __restrict__ Alog_b, const float* __restrict__ Db,
             const float* __restrict__ hIn,
             float* __restrict__ yf, float* __restrict__ yb) {
  int dirb = blockIdx.z;
  int dir = dirb >> 1, b = dirb & 1;
  int ch = blockIdx.y;
  int tid = threadIdx.x;
  int lane = tid & 63;
  int wv = tid >> 6;
  int ns = lane >> 4;
  int dl_ = lane & 15;
  int d = blockIdx.x * 64 + wv * 16 + dl_;
  const float* Alog = dir ? Alog_b : Alog_f;
  const float* Dp = dir ? Db : Df;
  float Av[4];
  #pragma unroll
  for (int j = 0; j < 4; ++j) Av[j] = -__expf(Alog[d * 16 + ns * 4 + j]);
  float Dvv = Dp[d];
  int l0 = ch * 64;
  size_t base = ((size_t)dir * ML + (size_t)b * LL + l0) * DI + d;
  const float* dptr = delta_all + base;
  const ushort* xptr = xc_all + base;
  const float* bc = dtBC_all + ((size_t)dir * ML + (size_t)b * LL + l0) * 80 + 48 + ns * 4;
  float* yo = dir ? yb : yf;
  size_t hi = (((size_t)dirb * 1536 + d) * 16 + ch) * 16 + ns * 4;
  f4 h0 = *(const f4*)(hIn + hi);
  float h[4] = {h0.x, h0.y, h0.z, h0.w};
  #pragma unroll 4
  for (int l = 0; l < 64; ++l) {
    float dl = dptr[(size_t)l * DI];
    float xv = bf2f(xptr[(size_t)l * DI]);
    f4 Bv = *(const f4*)(bc + l * 80);
    f4 Cv = *(const f4*)(bc + 16 + l * 80);
    float dbx = dl * xv;
    float pr = 0.f;
    #pragma unroll
    for (int j = 0; j < 4; ++j) {
      float dA = __expf(dl * Av[j]);
      h[j] = dA * h[j] + dbx * Bv[j];
      pr += h[j] * Cv[j];
    }
    pr += __shfl_xor(pr, 16);
    pr += __shfl_xor(pr, 32);
    if (ns == 0) {
      int gl = l0 + l;
      int lo = dir ? (LL - 1 - gl) : gl;
      yo[((size_t)b * LL + lo) * DI + d] = pr + xv * Dvv;
    }
  }
}

// y_bf = bf16((yf + yb) * silu(z)), vec4 over [2048][1536]
__global__ void k_gate(const float* __restrict__ a, const float* __restrict__ b,
                       const float* __restrict__ xz, ushort* __restrict__ o) {
  int i = blockIdx.x * 256 + threadIdx.x;   // 786432 f4 groups
  int row = i / 384;
  int c4 = i - row * 384;
  f4 va = *(const f4*)(a + (size_t)i * 4);
  f4 vb = *(const f4*)(b + (size_t)i * 4);
  f4 vz = *(const f4*)(xz + (size_t)row * N2 + DI + c4 * 4);
  ushort4 u;
  float s0 = vz.x / (1.f + __expf(-vz.x));
  float s1 = vz.y / (1.f + __expf(-vz.y));
  float s2 = vz.z / (1.f + __expf(-vz.z));
  float s3 = vz.w / (1.f + __expf(-vz.w));
  u.x = f2bf((va.x + vb.x) * s0);
  u.y = f2bf((va.y + vb.y) * s1);
  u.z = f2bf((va.z + vb.z) * s2);
  u.w = f2bf((va.w + vb.w) * s3);
  *(ushort4*)(o + (size_t)i * 4) = u;
}

extern "C" void kernel_launch(void* const* d_in, const int* in_sizes, int n_in,
                              void* d_out, int out_size, void* d_ws, size_t ws_size,
                              hipStream_t stream) {
  const float* hidden      = (const float*)d_in[0];
  const float* in_proj_w   = (const float*)d_in[1];
  const float* conv_w      = (const float*)d_in[2];
  const float* conv_b      = (const float*)d_in[3];
  const float* x_proj_w    = (const float*)d_in[4];
  const float* dt_proj_w   = (const float*)d_in[5];
  const float* dt_proj_b   = (const float*)d_in[6];
  const float* A_log       = (const float*)d_in[7];
  const float* Dv          = (const float*)d_in[8];
  const float* conv_w_b    = (const float*)d_in[9];
  const float* conv_b_b    = (const float*)d_in[10];
  const float* x_proj_w_b  = (const float*)d_in[11];
  const float* dt_proj_w_b = (const float*)d_in[12];
  const float* dt_proj_b_b = (const float*)d_in[13];
  const float* A_b_log     = (const float*)d_in[14];
  const float* D_b         = (const float*)d_in[15];
  const float* out_proj_w  = (const float*)d_in[16];
  float* out = (float*)d_out;

  // fp32 workspace layout (floats)
  float* wsf   = (float*)d_ws;
  float* xz    = wsf;               // 6291456  [2048][3072]
  float* dtBC  = wsf + 6291456;     // 2x163840 [2][2048][80]
  float* delta = wsf + 6619136;     // 2x3145728 [2][2048][1536]
  float* yf    = wsf + 12910592;    // 3145728
  float* yb    = wsf + 16056320;    // 3145728
  // bf16 workspace (ushorts), starts at byte 76808192
  ushort* wsb     = (ushort*)((char*)d_ws + 76808192);
  ushort* hid_bf  = wsb;                 // 1572864
  ushort* win_bf  = wsb + 1572864;       // 2359296
  ushort* xw_bf   = wsb + 3932160;       // 2x122880
  ushort* dtw_bf  = wsb + 4177920;       // 2x98304
  ushort* wout_bf = wsb + 4374528;       // 1179648
  ushort* xc_bf   = wsb + 5554176;       // 2x3145728
  ushort* dt_bf   = wsb + 11845632;      // 2x131072
  ushort* y_bf    = wsb + 12107776;      // 3145728
  if (ws_size < 107315200) return;       // need ~107.3 MB

  // overlays (liveness-disjoint with hosts):
  // xpart (x_proj split-K partials, 10.5 MB) -> yf region (dead until scan1's
  //   hL lands there after k_xred).
  // opart (out_proj split-K partials, 25.2 MB) -> delta region (dead after
  //   scan2; out_proj runs after k_gate).
  // hL -> yf, P -> yb, hIn -> y_bf (same liveness argument as before).
  float* xpart = yf;
  float* opart = delta;
  float* hL  = yf;
  float* P   = yb;
  float* hIn = (float*)y_bf;

  Cvt5 c5;
  c5.seg[0] = { hidden,      hid_bf,            1572864 / 4 };
  c5.seg[1] = { in_proj_w,   win_bf,            2359296 / 4 };
  c5.seg[2] = { x_proj_w,    xw_bf,             122880 / 4 };
  c5.seg[3] = { x_proj_w_b,  xw_bf + 122880,    122880 / 4 };
  c5.seg[4] = { out_proj_w,  wout_bf,           1179648 / 4 };
  k_cvt<<<CVT_BLOCKS + 768, 256, 0, stream>>>(c5, 1339392, dt_proj_w, dt_proj_w_b, dtw_bf);

  // xz = hidden @ in_proj_w.T   (2048 x 3072, K=768)
  k_gemm<0, false, 1><<<dim3(16, 24), 256, 0, stream>>>(
      hid_bf, win_bf, xz, 2048, 3072, 768, nullptr, nullptr, 0, 0, 0, 0, 0);

  // conv + silu, both dirs in one pass -> xc_bf
  k_conv2<<<dim3(LL / CONV_R, 2, 2), 192, 0, stream>>>(
      xz, conv_w, conv_b, conv_w_b, conv_b_b, xc_bf);

  // x_proj both dirs, split-K 8x192: (2048 x 80, K=1536) -> partials
  k_gemm<0, true, 8><<<dim3(16, 8, 2), 256, 0, stream>>>(
      xc_bf, xw_bf, xpart, 2048, 80, 1536, nullptr, nullptr,
      3145728, 122880, 1310720, 163840, 192);
  // reduce partials -> dtBC fp32 + dt_bf bf16 (padded)
  k_xred<<<320, 256, 0, stream>>>(xpart, dtBC, dt_bf);

  // dt_proj + bias + softplus, both dirs: (2048 x 1536, K=64 padded)
  k_gemm<1, false, 1><<<dim3(16, 12, 2), 256, 0, stream>>>(
      dt_bf, dtw_bf, delta, 2048, 1536, 64, dt_proj_b, dt_proj_b_b,
      131072, 98304, 3145728, 0, 0);

  // chunked scan: K1 (local states) -> combine -> K2 (seeded, fused epilogue)
  k_scan1<<<dim3(24, 16, 4), 256, 0, stream>>>(delta, xc_bf, dtBC, A_log, A_b_log, hL, P);
  k_comb<<<384, 256, 0, stream>>>(hL, P, hIn);
  k_scan2<<<dim3(24, 16, 4), 256, 0, stream>>>(delta, xc_bf, dtBC,
                                               A_log, Dv, A_b_log, D_b, hIn, yf, yb);

  // y_bf = bf16((yf + yb) * silu(z))
  k_gate<<<3072, 256, 0, stream>>>(yf, yb, xz, y_bf);

  // out = y @ out_proj_w.T  (2048 x 768, K=1536), split-K 4x384 -> partials
  k_gemm<0, false, 4><<<dim3(16, 24), 256, 0, stream>>>(
      y_bf, wout_bf, opart, 2048, 768, 1536, nullptr, nullptr,
      0, 0, 0, 1572864, 384);
  // reduce partials -> out
  k_ored<<<1536, 256, 0, stream>>>(opart, out);
}

// Round 8
// 277.178 us; speedup vs baseline: 4.1049x; 1.0166x over previous
//
#include <hip/hip_runtime.h>
#include <hip/hip_bf16.h>

#define LL 1024
#define DI 1536
#define N2 3072
#define ML 2048

typedef __attribute__((ext_vector_type(8))) short short8;
typedef __attribute__((ext_vector_type(4))) float f4;
typedef __attribute__((ext_vector_type(4))) float f32x4;

__device__ __forceinline__ ushort f2bf(float f) {
  union { float f; unsigned u; } v; v.f = f;
  unsigned u = v.u;
  u += 0x7fffu + ((u >> 16) & 1u);
  return (ushort)(u >> 16);
}
__device__ __forceinline__ float bf2f(ushort u) {
  union { unsigned i; float f; } w; w.i = ((unsigned)u) << 16; return w.f;
}
__device__ __forceinline__ f4 bf2f4(ushort4 u) {
  f4 r; r.x = bf2f(u.x); r.y = bf2f(u.y); r.z = bf2f(u.z); r.w = bf2f(u.w);
  return r;
}

// async global->LDS, 16B per lane; lds dest = wave-uniform base + lane*16
__device__ __forceinline__ void gload16(const ushort* g, ushort* l) {
  __builtin_amdgcn_global_load_lds(
      (const __attribute__((address_space(1))) unsigned int*)g,
      (__attribute__((address_space(3))) unsigned int*)l, 16, 0, 0);
}

struct CvtSeg { const float* s; ushort* d; int n4; };
struct Cvt5 { CvtSeg seg[5]; };

#define CVT_BLOCKS 5232

// merged: blocks [0,5232): fp32->bf16 over 5 segments; blocks [5232,6000):
// dt_proj weights (1536,48) -> bf16 [2][1536][64] zero-padded K
__global__ void k_cvt(Cvt5 p, int total4,
                      const float* __restrict__ wf, const float* __restrict__ wb,
                      ushort* __restrict__ dtw) {
  int bid = blockIdx.x;
  if (bid < CVT_BLOCKS) {
    int i = bid * 256 + threadIdx.x;
    if (i >= total4) return;
    int off = i, sidx = 0;
    while (sidx < 4 && off >= p.seg[sidx].n4) { off -= p.seg[sidx].n4; ++sidx; }
    f4 v = *(const f4*)(p.seg[sidx].s + (size_t)off * 4);
    ushort4 o;
    o.x = f2bf(v.x); o.y = f2bf(v.y); o.z = f2bf(v.z); o.w = f2bf(v.w);
    *(ushort4*)(p.seg[sidx].d + (size_t)off * 4) = o;
  } else {
    int i = (bid - CVT_BLOCKS) * 256 + threadIdx.x;   // 2*1536*64
    int c = i & 63;
    int rr = i >> 6;
    int dir = rr / 1536;
    int r = rr - dir * 1536;
    const float* w = dir ? wb : wf;
    dtw[i] = (c < 48) ? f2bf(w[r * 48 + c]) : (ushort)0;
  }
}

// 128x128 tile bf16 MFMA GEMM, m97 structure: global_load_lds(16B) staging
// into LINEAR LDS [128][32], C[m,n] = sum_k A[m,k]*B[n,k] (both K-major).
// EPI==0: plain. EPI==1: softplus(acc + bias[col]).
// OBF: output is bf16 (ushort), else fp32.
// KS>1: split-K, blockIdx.y = nt*KS + ks, K-range [ks*kLen,(ks+1)*kLen).
// NGUARD: N < 128 (x_proj, N=80) — B stages garbage rows >=N (memory-safe),
// guarded at C-write.
template<int EPI, bool NGUARD, int KS, bool OBF>
__global__ __launch_bounds__(256)
void k_gemm(const ushort* __restrict__ A, const ushort* __restrict__ Bm,
            void* __restrict__ Cp, int M, int N, int K,
            const float* __restrict__ bias, const float* __restrict__ bias2,
            size_t sA, size_t sB, size_t sC, size_t sKs, int kLen) {
  const int dir = blockIdx.z;
  A += (size_t)dir * sA;
  Bm += (size_t)dir * sB;
  size_t cbase = (size_t)dir * sC;
  const float* bp = (EPI == 1) ? (dir ? bias2 : bias) : nullptr;

  int n0, kOff, kEnd;
  if (KS > 1) {
    int yb_ = blockIdx.y;
    int nt = yb_ / KS, ks = yb_ - nt * KS;
    n0 = nt * 128;
    kOff = ks * kLen;
    kEnd = kOff + kLen;
    cbase += (size_t)ks * sKs;
  } else {
    n0 = blockIdx.y * 128;
    kOff = 0;
    kEnd = K;
  }

  __shared__ ushort As[128 * 32];   // linear, row-major [128][32]
  __shared__ ushort Bs[128 * 32];
  const int tid = threadIdx.x;
  const int m0 = blockIdx.x * 128;
  const int wv = tid >> 6;
  const int lane = tid & 63;
  const int wr = (wv >> 1) * 64;
  const int wc = (wv & 1) * 64;
  const int lr = lane & 15;
  const int lk = lane >> 4;
  f32x4 acc[4][4] = {};
  for (int k0 = kOff; k0 < kEnd; k0 += 32) {
    #pragma unroll
    for (int i = 0; i < 2; ++i) {
      int e = (tid + i * 256) * 8;
      int r = e >> 5;
      int c = e & 31;
      gload16(A + (size_t)(m0 + r) * K + k0 + c, &As[(i * 256 + wv * 64) * 8]);
      gload16(Bm + (size_t)(n0 + r) * K + k0 + c, &Bs[(i * 256 + wv * 64) * 8]);
    }
    __syncthreads();
    short8 af[4], bfr[4];
    #pragma unroll
    for (int m = 0; m < 4; ++m) af[m] = *(const short8*)(&As[(wr + m*16 + lr) * 32 + lk*8]);
    #pragma unroll
    for (int n = 0; n < 4; ++n) bfr[n] = *(const short8*)(&Bs[(wc + n*16 + lr) * 32 + lk*8]);
    #pragma unroll
    for (int m = 0; m < 4; ++m)
      #pragma unroll
      for (int n = 0; n < 4; ++n)
        acc[m][n] = __builtin_amdgcn_mfma_f32_16x16x32_bf16(af[m], bfr[n], acc[m][n], 0, 0, 0);
    __syncthreads();
  }
  #pragma unroll
  for (int m = 0; m < 4; ++m) {
    int gr = m0 + wr + m * 16 + lk * 4;
    #pragma unroll
    for (int n = 0; n < 4; ++n) {
      int gc = n0 + wc + n * 16 + lr;
      if (NGUARD && gc >= N) continue;
      #pragma unroll
      for (int r = 0; r < 4; ++r) {
        float v = acc[m][n][r];
        if (EPI == 1) {
          v += bp[gc];
          v = (v > 20.f) ? v : log1pf(__expf(v));
        }
        size_t idx = cbase + (size_t)(gr + r) * N + gc;
        if (OBF) ((ushort*)Cp)[idx] = f2bf(v);
        else     ((float*)Cp)[idx] = v;
      }
    }
  }
}

// split-K reduce for x_proj: sum 8 partials -> dtBC fp32; pack bf16 dt
// (cols<48 of the 80; zero-pad 48..63) -> dt_bf.
__global__ void k_xred(const float* __restrict__ partial,
                       float* __restrict__ dtBC, ushort* __restrict__ dtbf) {
  int i = blockIdx.x * 256 + threadIdx.x;   // 2*2048*20 = 81920
  int dir = i / 40960;
  int rem = i - dir * 40960;
  int row = rem / 20;
  int c4 = rem - row * 20;
  f4 s = {0.f, 0.f, 0.f, 0.f};
  #pragma unroll
  for (int ks = 0; ks < 8; ++ks) {
    f4 v = *(const f4*)(partial + (((size_t)(dir * 8 + ks) * 2048 + row) * 80 + c4 * 4));
    s.x += v.x; s.y += v.y; s.z += v.z; s.w += v.w;
  }
  *(f4*)(dtBC + ((size_t)dir * 163840 + (size_t)row * 80 + c4 * 4)) = s;
  if (c4 < 16) {
    ushort4 u;
    if (c4 < 12) { u.x = f2bf(s.x); u.y = f2bf(s.y); u.z = f2bf(s.z); u.w = f2bf(s.w); }
    else { u.x = 0; u.y = 0; u.z = 0; u.w = 0; }
    *(ushort4*)(dtbf + ((size_t)dir * 131072 + (size_t)row * 64 + c4 * 4)) = u;
  }
}

// split-K reduce for out_proj: sum 4 partials -> out
__global__ void k_ored(const float* __restrict__ part, float* __restrict__ out) {
  int i = blockIdx.x * 256 + threadIdx.x;   // 2048*768/4 = 393216
  f4 s = {0.f, 0.f, 0.f, 0.f};
  #pragma unroll
  for (int ks = 0; ks < 4; ++ks) {
    f4 v = *(const f4*)(part + (size_t)ks * 1572864 + (size_t)i * 4);
    s.x += v.x; s.y += v.y; s.z += v.z; s.w += v.w;
  }
  *(f4*)(out + (size_t)i * 4) = s;
}

// causal depthwise conv(K=4) + SiLU, BOTH dirs in one pass over bf16 xz.
#define CONV_R 8
__global__ __launch_bounds__(192)
void k_conv2(const ushort* __restrict__ xz,
             const float* __restrict__ wf, const float* __restrict__ bf_,
             const float* __restrict__ wb, const float* __restrict__ bb_,
             ushort* __restrict__ xcbf) {
  int d4 = blockIdx.z * 192 + threadIdx.x;   // 0..383
  int b = blockIdx.y;
  int l0 = blockIdx.x * CONV_R;
  int d = d4 * 4;
  f4 w0[4], w1[4];
  #pragma unroll
  for (int c = 0; c < 4; ++c) {
    w0[c] = *(const f4*)(wf + (size_t)d * 4 + c * 4);
    w1[c] = *(const f4*)(wb + (size_t)d * 4 + c * 4);
  }
  f4 bias0 = *(const f4*)(bf_ + d);
  f4 bias1 = *(const f4*)(bb_ + d);
  f4 win[CONV_R + 6];
  #pragma unroll
  for (int j = 0; j < CONV_R + 6; ++j) {
    int t = l0 - 3 + j;
    if (t >= 0 && t < LL) {
      win[j] = bf2f4(*(const ushort4*)(xz + ((size_t)(b * LL + t)) * N2 + d));
    } else {
      f4 z = {0.f, 0.f, 0.f, 0.f};
      win[j] = z;
    }
  }
  #pragma unroll
  for (int i = 0; i < CONV_R; ++i) {
    int l = l0 + i;
    float a0[4], a1[4];
    #pragma unroll
    for (int c = 0; c < 4; ++c) { a0[c] = bias0[c]; a1[c] = bias1[c]; }
    #pragma unroll
    for (int k = 0; k < 4; ++k) {
      f4 xv0 = win[i + k];        // x[l-3+k]
      f4 xv1 = win[i + 3 + k];    // x[l+k]
      #pragma unroll
      for (int c = 0; c < 4; ++c) {
        a0[c] += xv0[c] * w0[c][k];
        a1[c] += xv1[c] * w1[c][3 - k];
      }
    }
    ushort4 o0, o1;
    #pragma unroll
    for (int c = 0; c < 4; ++c) {
      a0[c] = a0[c] / (1.f + __expf(-a0[c]));
      a1[c] = a1[c] / (1.f + __expf(-a1[c]));
    }
    o0.x = f2bf(a0[0]); o0.y = f2bf(a0[1]); o0.z = f2bf(a0[2]); o0.w = f2bf(a0[3]);
    o1.x = f2bf(a1[0]); o1.y = f2bf(a1[1]); o1.z = f2bf(a1[2]); o1.w = f2bf(a1[3]);
    *(ushort4*)(xcbf + ((size_t)(b * LL + l)) * DI + d) = o0;
    *(ushort4*)(xcbf + ((size_t)(ML + b * LL + (LL - 1 - l))) * DI + d) = o1;
  }
}

// ---- chunked parallel scan: 16 chunks of 64 steps ----
// delta is bf16 now. K1: local scan from h=0 -> chunk-final hL; dA-product
// via exp(Av * sum(dl)) (exact reassociation).
__global__ __launch_bounds__(256)
void k_scan1(const ushort* __restrict__ delta_all,
             const ushort* __restrict__ xc_all,
             const float* __restrict__ dtBC_all,
             const float* __restrict__ Alog_f, const float* __restrict__ Alog_b,
             float* __restrict__ hL, float* __restrict__ P) {
  int dirb = blockIdx.z;               // 0..3
  int dir = dirb >> 1, b = dirb & 1;
  int ch = blockIdx.y;                 // 0..15
  int tid = threadIdx.x;
  int lane = tid & 63;
  int wv = tid >> 6;
  int ns = lane >> 4;                  // state group 0..3
  int dl_ = lane & 15;
  int d = blockIdx.x * 64 + wv * 16 + dl_;
  const float* Alog = dir ? Alog_b : Alog_f;
  float Av[4];
  #pragma unroll
  for (int j = 0; j < 4; ++j) Av[j] = -__expf(Alog[d * 16 + ns * 4 + j]);
  int l0 = ch * 64;
  size_t base = ((size_t)dir * ML + (size_t)b * LL + l0) * DI + d;
  const ushort* dptr = delta_all + base;
  const ushort* xptr = xc_all + base;
  const float* bc = dtBC_all + ((size_t)dir * ML + (size_t)b * LL + l0) * 80 + 48 + ns * 4;
  float h[4] = {0.f, 0.f, 0.f, 0.f};
  float s = 0.f;
  #pragma unroll 4
  for (int l = 0; l < 64; ++l) {
    float dl = bf2f(dptr[(size_t)l * DI]);
    float xv = bf2f(xptr[(size_t)l * DI]);
    f4 Bv = *(const f4*)(bc + l * 80);
    float dbx = dl * xv;
    s += dl;
    #pragma unroll
    for (int j = 0; j < 4; ++j) {
      float dA = __expf(dl * Av[j]);
      h[j] = dA * h[j] + dbx * Bv[j];
    }
  }
  size_t si = (((size_t)dirb * 1536 + d) * 16 + ch) * 16 + ns * 4;
  f4 hv = {h[0], h[1], h[2], h[3]};
  f4 pv = {__expf(Av[0] * s), __expf(Av[1] * s), __expf(Av[2] * s), __expf(Av[3] * s)};
  *(f4*)(hL + si) = hv;
  *(f4*)(P + si) = pv;
}

// combine: per (channel,n), sequential over 16 chunks -> h_in per chunk
__global__ void k_comb(const float* __restrict__ hL, const float* __restrict__ P,
                       float* __restrict__ hIn) {
  int tid = blockIdx.x * 256 + threadIdx.x;   // 6144*16 = 98304
  int n = tid & 15;
  size_t c = tid >> 4;
  float h = 0.f;
  size_t base = c * 256 + n;
  #pragma unroll
  for (int ch = 0; ch < 16; ++ch) {
    hIn[base + ch * 16] = h;
    h = P[base + ch * 16] * h + hL[base + ch * 16];
  }
}

// K2: rerun local scan seeded with h_in; fused C-contraction + D.
// Writes RAW y as bf16 (z-gating in k_gate). 2 shuffles per step.
__global__ __launch_bounds__(256)
void k_scan2(const ushort* __restrict__ delta_all,
             const ushort* __restrict__ xc_all,
             const float* __restrict__ dtBC_all,
             const float* __restrict__ Alog_f, const float* __restrict__ Df,
             const float* __restrict__ Alog_b, const float* __restrict__ Db,
             const float* __restrict__ hIn,
             ushort* __restrict__ yf, ushort* __restrict__ yb) {
  int dirb = blockIdx.z;
  int dir = dirb >> 1, b = dirb & 1;
  int ch = blockIdx.y;
  int tid = threadIdx.x;
  int lane = tid & 63;
  int wv = tid >> 6;
  int ns = lane >> 4;
  int dl_ = lane & 15;
  int d = blockIdx.x * 64 + wv * 16 + dl_;
  const float* Alog = dir ? Alog_b : Alog_f;
  const float* Dp = dir ? Db : Df;
  float Av[4];
  #pragma unroll
  for (int j = 0; j < 4; ++j) Av[j] = -__expf(Alog[d * 16 + ns * 4 + j]);
  float Dvv = Dp[d];
  int l0 = ch * 64;
  size_t base = ((size_t)dir * ML + (size_t)b * LL + l0) * DI + d;
  const ushort* dptr = delta_all + base;
  const ushort* xptr = xc_all + base;
  const float* bc = dtBC_all + ((size_t)dir * ML + (size_t)b * LL + l0) * 80 + 48 + ns * 4;
  ushort* yo = dir ? yb : yf;
  size_t hi = (((size_t)dirb * 1536 + d) * 16 + ch) * 16 + ns * 4;
  f4 h0 = *(const f4*)(hIn + hi);
  float h[4] = {h0.x, h0.y, h0.z, h0.w};
  #pragma unroll 4
  for (int l = 0; l < 64; ++l) {
    float dl = bf2f(dptr[(size_t)l * DI]);
    float xv = bf2f(xptr[(size_t)l * DI]);
    f4 Bv = *(const f4*)(bc + l * 80);
    f4 Cv = *(const f4*)(bc + 16 + l * 80);
    float dbx = dl * xv;
    float pr = 0.f;
    #pragma unroll
    for (int j = 0; j < 4; ++j) {
      float dA = __expf(dl * Av[j]);
      h[j] = dA * h[j] + dbx * Bv[j];
      pr += h[j] * Cv[j];
    }
    pr += __shfl_xor(pr, 16);
    pr += __shfl_xor(pr, 32);
    if (ns == 0) {
      int gl = l0 + l;
      int lo = dir ? (LL - 1 - gl) : gl;
      yo[((size_t)b * LL + lo) * DI + d] = f2bf(pr + xv * Dvv);
    }
  }
}

// y_bf = bf16((yf + yb) * silu(z)), all bf16 in, vec4 over [2048][1536]
__global__ void k_gate(const ushort* __restrict__ a, const ushort* __restrict__ b,
                       const ushort* __restrict__ xz, ushort* __restrict__ o) {
  int i = blockIdx.x * 256 + threadIdx.x;   // 786432 groups of 4
  int row = i / 384;
  int c4 = i - row * 384;
  f4 va = bf2f4(*(const ushort4*)(a + (size_t)i * 4));
  f4 vb = bf2f4(*(const ushort4*)(b + (size_t)i * 4));
  f4 vz = bf2f4(*(const ushort4*)(xz + (size_t)row * N2 + DI + c4 * 4));
  ushort4 u;
  float s0 = vz.x / (1.f + __expf(-vz.x));
  float s1 = vz.y / (1.f + __expf(-vz.y));
  float s2 = vz.z / (1.f + __expf(-vz.z));
  float s3 = vz.w / (1.f + __expf(-vz.w));
  u.x = f2bf((va.x + vb.x) * s0);
  u.y = f2bf((va.y + vb.y) * s1);
  u.z = f2bf((va.z + vb.z) * s2);
  u.w = f2bf((va.w + vb.w) * s3);
  *(ushort4*)(o + (size_t)i * 4) = u;
}

extern "C" void kernel_launch(void* const* d_in, const int* in_sizes, int n_in,
                              void* d_out, int out_size, void* d_ws, size_t ws_size,
                              hipStream_t stream) {
  const float* hidden      = (const float*)d_in[0];
  const float* in_proj_w   = (const float*)d_in[1];
  const float* conv_w      = (const float*)d_in[2];
  const float* conv_b      = (const float*)d_in[3];
  const float* x_proj_w    = (const float*)d_in[4];
  const float* dt_proj_w   = (const float*)d_in[5];
  const float* dt_proj_b   = (const float*)d_in[6];
  const float* A_log       = (const float*)d_in[7];
  const float* Dv          = (const float*)d_in[8];
  const float* conv_w_b    = (const float*)d_in[9];
  const float* conv_b_b    = (const float*)d_in[10];
  const float* x_proj_w_b  = (const float*)d_in[11];
  const float* dt_proj_w_b = (const float*)d_in[12];
  const float* dt_proj_b_b = (const float*)d_in[13];
  const float* A_b_log     = (const float*)d_in[14];
  const float* D_b         = (const float*)d_in[15];
  const float* out_proj_w  = (const float*)d_in[16];
  float* out = (float*)d_out;

  // ---- workspace layout (93.4 MB total) ----
  // fp32 block: 6291456 floats (25.2 MB), with internal overlays:
  //   dtBC @0 (327680), hL @327680, P @1900544, hIn @3473408 (ends 5046272)
  //   xpart @327680 (2621440 fl; live x_proj->xred, before hL/P written)
  //   opart @0 (6291456 fl; live out_proj->ored, after all others dead)
  float* wsf   = (float*)d_ws;
  float* dtBC  = wsf;
  float* hL    = wsf + 327680;
  float* P     = wsf + 1900544;
  float* hIn   = wsf + 3473408;
  float* xpart = wsf + 327680;
  float* opart = wsf;
  // bf16 block at byte 25165824:
  ushort* wsb      = (ushort*)((char*)d_ws + 25165824);
  ushort* hid_bf   = wsb;                  // 1572864
  ushort* win_bf   = wsb + 1572864;        // 2359296
  ushort* xw_bf    = wsb + 3932160;        // 2x122880
  ushort* dtw_bf   = wsb + 4177920;        // 196608
  ushort* wout_bf  = wsb + 4374528;        // 1179648
  ushort* xz_bf    = wsb + 5554176;        // 6291456 [2048][3072]
  ushort* xc_bf    = wsb + 11845632;       // 2x3145728
  ushort* dt_bf    = wsb + 18137088;       // 262144
  ushort* delta_bf = wsb + 18399232;       // 2x3145728
  ushort* ybf_f    = wsb + 24690688;       // 3145728
  ushort* ybf_b    = wsb + 27836416;       // 3145728
  ushort* y_bf     = wsb + 30982144;       // 3145728 (ends 34127872)
  if (ws_size < 93421568) return;

  Cvt5 c5;
  c5.seg[0] = { hidden,      hid_bf,            1572864 / 4 };
  c5.seg[1] = { in_proj_w,   win_bf,            2359296 / 4 };
  c5.seg[2] = { x_proj_w,    xw_bf,             122880 / 4 };
  c5.seg[3] = { x_proj_w_b,  xw_bf + 122880,    122880 / 4 };
  c5.seg[4] = { out_proj_w,  wout_bf,           1179648 / 4 };
  k_cvt<<<CVT_BLOCKS + 768, 256, 0, stream>>>(c5, 1339392, dt_proj_w, dt_proj_w_b, dtw_bf);

  // xz = hidden @ in_proj_w.T  (2048 x 3072, K=768) -> bf16
  k_gemm<0, false, 1, true><<<dim3(16, 24), 256, 0, stream>>>(
      hid_bf, win_bf, xz_bf, 2048, 3072, 768, nullptr, nullptr, 0, 0, 0, 0, 0);

  // conv + silu, both dirs in one pass -> xc_bf
  k_conv2<<<dim3(LL / CONV_R, 2, 2), 192, 0, stream>>>(
      xz_bf, conv_w, conv_b, conv_w_b, conv_b_b, xc_bf);

  // x_proj both dirs, split-K 8x192 -> fp32 partials
  k_gemm<0, true, 8, false><<<dim3(16, 8, 2), 256, 0, stream>>>(
      xc_bf, xw_bf, xpart, 2048, 80, 1536, nullptr, nullptr,
      3145728, 122880, 1310720, 163840, 192);
  k_xred<<<320, 256, 0, stream>>>(xpart, dtBC, dt_bf);

  // dt_proj + bias + softplus, both dirs -> bf16 delta
  k_gemm<1, false, 1, true><<<dim3(16, 12, 2), 256, 0, stream>>>(
      dt_bf, dtw_bf, delta_bf, 2048, 1536, 64, dt_proj_b, dt_proj_b_b,
      131072, 98304, 3145728, 0, 0);

  // chunked scan: K1 -> combine -> K2
  k_scan1<<<dim3(24, 16, 4), 256, 0, stream>>>(delta_bf, xc_bf, dtBC, A_log, A_b_log, hL, P);
  k_comb<<<384, 256, 0, stream>>>(hL, P, hIn);
  k_scan2<<<dim3(24, 16, 4), 256, 0, stream>>>(delta_bf, xc_bf, dtBC,
                                               A_log, Dv, A_b_log, D_b, hIn, ybf_f, ybf_b);

  // y_bf = bf16((yf + yb) * silu(z))
  k_gate<<<3072, 256, 0, stream>>>(ybf_f, ybf_b, xz_bf, y_bf);

  // out = y @ out_proj_w.T  (2048 x 768, K=1536), split-K 4x384 -> partials
  k_gemm<0, false, 4, false><<<dim3(16, 24), 256, 0, stream>>>(
      y_bf, wout_bf, opart, 2048, 768, 1536, nullptr, nullptr,
      0, 0, 0, 1572864, 384);
  k_ored<<<1536, 256, 0, stream>>>(opart, out);
}